// Round 10
// baseline (246.921 us; speedup 1.0000x reference)
//
#include <hip/hip_runtime.h>
#include <stdint.h>

typedef unsigned short u16;
typedef __attribute__((ext_vector_type(4))) float f32x4;
typedef __attribute__((ext_vector_type(8))) short bfrag;

static __device__ __forceinline__ u16 f2bf(float f) {  // RNE
  union { float f; uint32_t u; } v; v.f = f;
  return (u16)((v.u + 0x7fffu + ((v.u >> 16) & 1u)) >> 16);
}
// pack two f32 -> packed bf16x2 (RNE) in one instruction
static __device__ __forceinline__ uint32_t cvtpk(float lo, float hi) {
  uint32_t r;
  asm("v_cvt_pk_bf16_f32 %0, %1, %2" : "=v"(r) : "v"(lo), "v"(hi));
  return r;
}
// pack two f32 -> packed bf16x2 (round-half-up) in one v_perm
static __device__ __forceinline__ uint32_t pk2bf(float lo, float hi) {
  union { float f; uint32_t u; } a, b; a.f = lo; b.f = hi;
  return __builtin_amdgcn_perm(b.u + 0x8000u, a.u + 0x8000u, 0x07060302u);
}

#define GLOAD16(gp, lp)                                              \
  __builtin_amdgcn_global_load_lds(                                  \
      (const __attribute__((address_space(1))) uint32_t*)(gp),       \
      (__attribute__((address_space(3))) uint32_t*)(lp), 16, 0, 0)

// ---------------- pack W: [1024][64] f32 slice -> Wt[h*64+e][k] bf16
__global__ __launch_bounds__(256) void pack_w_hde(const float* __restrict__ W,
                                                  u16* __restrict__ Wt) {
  __shared__ float tile[64][65];
  const int h = blockIdx.y, k0 = blockIdx.x * 64;
  const int tid = threadIdx.x;
#pragma unroll
  for (int j = 0; j < 4; ++j) {
    int idx = tid + j * 256;
    int rr = idx >> 4, c4 = (idx & 15) * 4;
    const float4 v = *(const float4*)(W + (size_t)h * 65536 + (size_t)(k0 + rr) * 64 + c4);
    tile[rr][c4 + 0] = v.x; tile[rr][c4 + 1] = v.y;
    tile[rr][c4 + 2] = v.z; tile[rr][c4 + 3] = v.w;
  }
  __syncthreads();
#pragma unroll
  for (int j = 0; j < 4; ++j) {
    int idx = tid + j * 256;
    int ee = idx >> 4, c4 = (idx & 15) * 4;
    uint2 u;
    u.x = f2bf(tile[c4 + 0][ee]) | ((uint32_t)f2bf(tile[c4 + 1][ee]) << 16);
    u.y = f2bf(tile[c4 + 2][ee]) | ((uint32_t)f2bf(tile[c4 + 3][ee]) << 16);
    *(uint2*)(Wt + (size_t)(h * 64 + ee) * 1024 + k0 + c4) = u;
  }
}

// ---------------- transpose Wo: [1024][1024] f32 -> bf16, out[n][k] = Wo[k][n]
__global__ __launch_bounds__(256) void transpose_w(const float* __restrict__ W,
                                                   u16* __restrict__ Wt) {
  __shared__ float tile[64][65];
  const int k0 = blockIdx.x * 64, n0 = blockIdx.y * 64;
  const int tid = threadIdx.x;
#pragma unroll
  for (int j = 0; j < 4; ++j) {
    int idx = tid + j * 256;
    int rr = idx >> 4, c4 = (idx & 15) * 4;
    const float4 v = *(const float4*)(W + (size_t)(k0 + rr) * 1024 + n0 + c4);
    tile[rr][c4 + 0] = v.x; tile[rr][c4 + 1] = v.y;
    tile[rr][c4 + 2] = v.z; tile[rr][c4 + 3] = v.w;
  }
  __syncthreads();
#pragma unroll
  for (int j = 0; j < 4; ++j) {
    int idx = tid + j * 256;
    int ee = idx >> 4, c4 = (idx & 15) * 4;
    uint2 u;
    u.x = f2bf(tile[c4 + 0][ee]) | ((uint32_t)f2bf(tile[c4 + 1][ee]) << 16);
    u.y = f2bf(tile[c4 + 2][ee]) | ((uint32_t)f2bf(tile[c4 + 3][ee]) << 16);
    *(uint2*)(Wt + (size_t)(n0 + ee) * 1024 + k0 + c4) = u;
  }
}

// ---------------- fused QKV GEMM: [8192,1024]f32 x Wqkv^T[3072][1024] + bias
// 2-phase pipelined, 1 barrier/K-step. Q chunk pre-scaled by 0.125.
__global__ __launch_bounds__(256) void gemm_qkv(
    const float* __restrict__ Aq, const float* __restrict__ Ak,
    const float* __restrict__ Avv, const u16* __restrict__ Bt,
    const float* __restrict__ bq, const float* __restrict__ bk,
    const float* __restrict__ bv,
    u16* __restrict__ Qb, u16* __restrict__ Kb, u16* __restrict__ Vt) {
  __shared__ u16 As[2][128 * 40];
  __shared__ u16 Bs[2][128 * 32];
  const int tid = threadIdx.x;
  const int n = blockIdx.x;
  const int xcd = n & 7, j = n >> 3;
  const int mb = xcd * 8 + (j & 7);   // 0..63
  const int nb = j >> 3;              // 0..23
  const int chunk = nb >> 3;          // 0:Q 1:K 2:V
  const float* Af = (chunk == 0) ? Aq : (chunk == 1) ? Ak : Avv;
  const int wid = tid >> 6, lane = tid & 63;
  const int wr = wid >> 1, wc = wid & 1;
  const int g = lane >> 4, l15 = lane & 15;
  f32x4 acc[4][4] = {};

  const u16* Bg = Bt + (size_t)(nb * 128 + 2 * wid * 16 + (lane >> 2)) * 1024 + (lane & 3) * 8;
  const float* Ap = Af + (size_t)(mb * 128 + (tid >> 2)) * 1024 + (tid & 3) * 8;
  const int arow = tid >> 2, ac8 = (tid & 3) * 8;

  float4 fa[2][2];
#pragma unroll
  for (int c = 0; c < 2; ++c) {
    fa[c][0] = *(const float4*)(Ap + (size_t)c * 64 * 1024);
    fa[c][1] = *(const float4*)(Ap + (size_t)c * 64 * 1024 + 4);
  }
#pragma unroll
  for (int c = 0; c < 2; ++c)
    GLOAD16(Bg + (size_t)c * 16 * 1024, &Bs[0][2 * wid * 512 + c * 512]);
#pragma unroll
  for (int c = 0; c < 2; ++c) {
    uint4 u;
    u.x = pk2bf(fa[c][0].x, fa[c][0].y); u.y = pk2bf(fa[c][0].z, fa[c][0].w);
    u.z = pk2bf(fa[c][1].x, fa[c][1].y); u.w = pk2bf(fa[c][1].z, fa[c][1].w);
    *(uint4*)&As[0][(arow + c * 64) * 40 + ac8] = u;
  }
  __syncthreads();
  int cur = 0;
  for (int kk = 0; kk < 32; ++kk) {
    if (kk < 31) {
      const int kn = (kk + 1) * 32;
#pragma unroll
      for (int c = 0; c < 2; ++c) {
        fa[c][0] = *(const float4*)(Ap + (size_t)c * 64 * 1024 + kn);
        fa[c][1] = *(const float4*)(Ap + (size_t)c * 64 * 1024 + kn + 4);
      }
#pragma unroll
      for (int c = 0; c < 2; ++c)
        GLOAD16(Bg + (size_t)c * 16 * 1024 + kn, &Bs[cur ^ 1][2 * wid * 512 + c * 512]);
    }
    bfrag a[4], b[4];
#pragma unroll
    for (int m = 0; m < 4; ++m)
      a[m] = __builtin_bit_cast(bfrag, *(const uint4*)&As[cur][(wr * 64 + m * 16 + l15) * 40 + g * 8]);
#pragma unroll
    for (int nn = 0; nn < 4; ++nn)
      b[nn] = __builtin_bit_cast(bfrag, *(const uint4*)&Bs[cur][(wc * 64 + nn * 16 + l15) * 32 + g * 8]);
    __builtin_amdgcn_s_setprio(1);
#pragma unroll
    for (int m = 0; m < 4; ++m)
#pragma unroll
      for (int nn = 0; nn < 4; ++nn)
        acc[m][nn] = __builtin_amdgcn_mfma_f32_16x16x32_bf16(a[m], b[nn], acc[m][nn], 0, 0, 0);
    __builtin_amdgcn_s_setprio(0);
    if (kk < 31) {
#pragma unroll
      for (int c = 0; c < 2; ++c) {
        uint4 u;
        u.x = pk2bf(fa[c][0].x, fa[c][0].y); u.y = pk2bf(fa[c][0].z, fa[c][0].w);
        u.z = pk2bf(fa[c][1].x, fa[c][1].y); u.w = pk2bf(fa[c][1].z, fa[c][1].w);
        *(uint4*)&As[cur ^ 1][(arow + c * 64) * 40 + ac8] = u;
      }
      __syncthreads();
      cur ^= 1;
    }
  }

  const int row0 = mb * 128 + wr * 64 + g * 4;
  const int cc0 = (nb & 7) * 128 + wc * 64 + l15;  // col within chunk, 0..1023
  const float* bias = (chunk == 0) ? bq : (chunk == 1) ? bk : bv;
  const float qs = (chunk == 0) ? 0.125f : 1.0f;
#pragma unroll
  for (int m = 0; m < 4; ++m) {
#pragma unroll
    for (int nn = 0; nn < 4; ++nn) {
      const int row = row0 + m * 16;
      const int cc = cc0 + nn * 16;
      const float bcv = bias[cc];
      if (chunk < 2) {
        u16* dst = (chunk == 0) ? Qb : Kb;
#pragma unroll
        for (int r = 0; r < 4; ++r)
          dst[(size_t)(row + r) * 1024 + cc] = f2bf((acc[m][nn][r] + bcv) * qs);
      } else {
        u16 w[4];
#pragma unroll
        for (int r = 0; r < 4; ++r) w[r] = f2bf(acc[m][nn][r] + bcv);
        const size_t dst =
            ((size_t)((row >> 11) * 16 + (cc >> 6)) * 64 + (cc & 63)) * 2048 + (row & 2047);
        *(uint2*)(Vt + dst) = *(const uint2*)w;
      }
    }
  }
}

// ---------------- O-projection GEMM: Ob bf16 [8192,1024] x Wot^T + bo -> f32
__global__ __launch_bounds__(256) void gemm_o(const u16* __restrict__ Abf,
                                              const u16* __restrict__ Bt,
                                              const float* __restrict__ bo,
                                              float* __restrict__ Of) {
  __shared__ u16 As[2][128 * 32];
  __shared__ u16 Bs[2][128 * 32];
  const int tid = threadIdx.x;
  const int n = blockIdx.x;
  const int xcd = n & 7, j = n >> 3;
  const int mb = xcd * 8 + (j & 7);   // 0..63
  const int nb = j >> 3;              // 0..7
  const int wid = tid >> 6, lane = tid & 63;
  const int wr = wid >> 1, wc = wid & 1;
  const int g = lane >> 4, l15 = lane & 15;
  f32x4 acc[4][4] = {};

  const u16* Bg = Bt + (size_t)(nb * 128 + 2 * wid * 16 + (lane >> 2)) * 1024 + (lane & 3) * 8;
  const u16* Ag = Abf + (size_t)(mb * 128 + 2 * wid * 16 + (lane >> 2)) * 1024 + (lane & 3) * 8;

#pragma unroll
  for (int c = 0; c < 2; ++c) {
    GLOAD16(Ag + (size_t)c * 16 * 1024, &As[0][2 * wid * 512 + c * 512]);
    GLOAD16(Bg + (size_t)c * 16 * 1024, &Bs[0][2 * wid * 512 + c * 512]);
  }
  __syncthreads();
  int cur = 0;
  for (int kk = 0; kk < 32; ++kk) {
    if (kk < 31) {
      const int kn = (kk + 1) * 32;
#pragma unroll
      for (int c = 0; c < 2; ++c) {
        GLOAD16(Ag + (size_t)c * 16 * 1024 + kn, &As[cur ^ 1][2 * wid * 512 + c * 512]);
        GLOAD16(Bg + (size_t)c * 16 * 1024 + kn, &Bs[cur ^ 1][2 * wid * 512 + c * 512]);
      }
    }
    bfrag a[4], b[4];
#pragma unroll
    for (int m = 0; m < 4; ++m)
      a[m] = __builtin_bit_cast(bfrag, *(const uint4*)&As[cur][(wr * 64 + m * 16 + l15) * 32 + g * 8]);
#pragma unroll
    for (int nn = 0; nn < 4; ++nn)
      b[nn] = __builtin_bit_cast(bfrag, *(const uint4*)&Bs[cur][(wc * 64 + nn * 16 + l15) * 32 + g * 8]);
    __builtin_amdgcn_s_setprio(1);
#pragma unroll
    for (int m = 0; m < 4; ++m)
#pragma unroll
      for (int nn = 0; nn < 4; ++nn)
        acc[m][nn] = __builtin_amdgcn_mfma_f32_16x16x32_bf16(a[m], b[nn], acc[m][nn], 0, 0, 0);
    __builtin_amdgcn_s_setprio(0);
    if (kk < 31) { __syncthreads(); cur ^= 1; }
  }

  const int row0 = mb * 128 + wr * 64 + g * 4;
  const int col0 = nb * 128 + wc * 64 + l15;
#pragma unroll
  for (int m = 0; m < 4; ++m)
#pragma unroll
    for (int nn = 0; nn < 4; ++nn) {
      const int row = row0 + m * 16, col = col0 + nn * 16;
      const float bcv = bo[col];
#pragma unroll
      for (int r = 0; r < 4; ++r)
        Of[(size_t)(row + r) * 1024 + col] = acc[m][nn][r] + bcv;
    }
}

// ---------------- fused causal flash attention — swapped operands, zero LDS,
// register-double-buffered K (T14 async-issue split).
// Q (pre-scaled 1/8), K bf16 [B*S,1024]; Vtg bf16 [B*H][64e][2048s]; O bf16.
// 4096 blocks x 64 thr: ONE wave per block, one 32-row q-tile per wave.
// Per step: issue V(s) loads, then K(s+1) prefetch, then QK on K(s) --
// the K wait retires with 16 newer loads in flight, so K latency hides
// under softmax+PV+QK and V latency under QK+softmax.
__global__ __launch_bounds__(64) void attn_fused(const u16* __restrict__ Qb,
                                                 const u16* __restrict__ Kb,
                                                 const u16* __restrict__ Vtg,
                                                 u16* __restrict__ Ob) {
  const int lane = threadIdx.x & 63;
  const int g = lane >> 4, l15 = lane & 15;
  const int n = blockIdx.x;
  const int xcd = n & 7, j = n >> 3;     // j 0..511
  const int bh = xcd * 8 + (j & 7);
  const int t = 63 - (j >> 3);           // tile 0..63, longest first
  const int b = bh >> 4, h = bh & 15;
  const size_t baserow = (size_t)b * 2048;
  const u16* Qg = Qb + baserow * 1024 + h * 64;
  const u16* Kg = Kb + baserow * 1024 + h * 64;
  const u16* Vg = Vtg + (size_t)bh * 64 * 2048;
  u16* Og = Ob + baserow * 1024 + h * 64;

  const int q0 = t * 32;
  const int qrow = q0 + l15;             // this lane's q for qf=0 (+16 for qf=1)

  bfrag qa[2][2];
#pragma unroll
  for (int qf = 0; qf < 2; ++qf)
#pragma unroll
    for (int kh = 0; kh < 2; ++kh)
      qa[qf][kh] = __builtin_bit_cast(bfrag,
          *(const uint4*)(Qg + (size_t)(q0 + qf * 16 + l15) * 1024 + kh * 32 + g * 8));

  f32x4 accT[2][4] = {};      // [qf][et]: lane holds e=et*16+g*4+r, q=l15
  float M[2] = {-1e30f, -1e30f}, Ll[2] = {0.f, 0.f};

  const int s0lane = ((g & 1) << 5) | l15;   // source lane for frag u0/u1
  const int s1lane = s0lane + 16;            // source lane for frag u2/u3
  const bool ghi = (g >= 2);

  const int nsteps = (q0 >> 6) + 1;

  // K fragment row pointer for this lane (row = kv + tt*16 + l15)
  const u16* Krow = Kg + (size_t)l15 * 1024 + g * 8;

  bfrag kcur[2][4], knxt[2][4];
#pragma unroll
  for (int tt = 0; tt < 4; ++tt)
#pragma unroll
    for (int kh = 0; kh < 2; ++kh)
      kcur[kh][tt] = __builtin_bit_cast(bfrag,
          *(const uint4*)(Krow + (size_t)(tt * 16) * 1024 + kh * 32));

  for (int s = 0; s < nsteps; ++s) {
    const int kv0 = s << 6;
    const bool diag = (s == nsteps - 1);

    // V loads for this step (oldest outstanding)
    bfrag vb[2][4];
#pragma unroll
    for (int et = 0; et < 4; ++et)
#pragma unroll
      for (int kc = 0; kc < 2; ++kc)
        vb[kc][et] = __builtin_bit_cast(bfrag,
            *(const uint4*)(Vg + (size_t)(et * 16 + l15) * 2048 + kv0 + kc * 32 + g * 8));

    // K(s+1) prefetch (stays in flight across this whole step)
    if (s + 1 < nsteps) {
      const int kn = (s + 1) << 6;
#pragma unroll
      for (int tt = 0; tt < 4; ++tt)
#pragma unroll
        for (int kh = 0; kh < 2; ++kh)
          knxt[kh][tt] = __builtin_bit_cast(bfrag,
              *(const uint4*)(Krow + (size_t)(kn + tt * 16) * 1024 + kh * 32));
    }

    // S^T = K * Q^T : lane (g,l15) holds S[q=q0+qf*16+l15][kv0+tt*16+g*4+r]
    f32x4 sc[2][4];
    __builtin_amdgcn_s_setprio(1);
#pragma unroll
    for (int qf = 0; qf < 2; ++qf)
#pragma unroll
      for (int tt = 0; tt < 4; ++tt) {
        f32x4 z = {0.f, 0.f, 0.f, 0.f};
        z = __builtin_amdgcn_mfma_f32_16x16x32_bf16(kcur[0][tt], qa[qf][0], z, 0, 0, 0);
        z = __builtin_amdgcn_mfma_f32_16x16x32_bf16(kcur[1][tt], qa[qf][1], z, 0, 0, 0);
        sc[qf][tt] = z;
      }
    __builtin_amdgcn_s_setprio(0);

#pragma unroll
    for (int qf = 0; qf < 2; ++qf) {
      if (diag) {
        const int qq = qrow + qf * 16;
#pragma unroll
        for (int tt = 0; tt < 4; ++tt) {
          const int kvb = kv0 + tt * 16 + g * 4;
#pragma unroll
          for (int r = 0; r < 4; ++r)
            sc[qf][tt][r] = (kvb + r <= qq) ? sc[qf][tt][r] : -1e30f;
        }
      }
      // lane-local max over 16 values
      float m01 = fmaxf(fmaxf(sc[qf][0][0], sc[qf][0][1]), fmaxf(sc[qf][0][2], sc[qf][0][3]));
      float m23 = fmaxf(fmaxf(sc[qf][1][0], sc[qf][1][1]), fmaxf(sc[qf][1][2], sc[qf][1][3]));
      float m45 = fmaxf(fmaxf(sc[qf][2][0], sc[qf][2][1]), fmaxf(sc[qf][2][2], sc[qf][2][3]));
      float m67 = fmaxf(fmaxf(sc[qf][3][0], sc[qf][3][1]), fmaxf(sc[qf][3][2], sc[qf][3][3]));
      const float mloc = fmaxf(fmaxf(m01, m23), fmaxf(m45, m67));
      if (!__all(mloc - M[qf] <= 6.0f)) {  // rare: true row max + rescale
        float mr = fmaxf(mloc, __shfl_xor(mloc, 16));
        mr = fmaxf(mr, __shfl_xor(mr, 32));
        const float Mn = fmaxf(M[qf], mr);
        const float cf = __expf(M[qf] - Mn);
        M[qf] = Mn;
        Ll[qf] *= cf;
#pragma unroll
        for (int et = 0; et < 4; ++et)
#pragma unroll
          for (int r = 0; r < 4; ++r) accT[qf][et][r] *= cf;
      }
      // exp + lane-local L accumulation + bf16 pair packing
      uint32_t pk[4][2];
      float ss = 0.f;
#pragma unroll
      for (int tt = 0; tt < 4; ++tt) {
        float p0 = __expf(sc[qf][tt][0] - M[qf]);
        float p1 = __expf(sc[qf][tt][1] - M[qf]);
        float p2 = __expf(sc[qf][tt][2] - M[qf]);
        float p3 = __expf(sc[qf][tt][3] - M[qf]);
        ss += (p0 + p1) + (p2 + p3);
        pk[tt][0] = cvtpk(p0, p1);
        pk[tt][1] = cvtpk(p2, p3);
      }
      Ll[qf] += ss;
      // build P^T B-operand fragments via lane shuffles:
      // target lane (g,l15) kc-frag holds kv = kc*32 + g*8 .. +7 for q=l15.
      __builtin_amdgcn_s_setprio(1);
#pragma unroll
      for (int kc = 0; kc < 2; ++kc) {
        const int lo = kc * 2, hi = kc * 2 + 1;
        const uint32_t a0 = __shfl(pk[lo][0], s0lane), b0 = __shfl(pk[hi][0], s0lane);
        const uint32_t a1 = __shfl(pk[lo][1], s0lane), b1 = __shfl(pk[hi][1], s0lane);
        const uint32_t a2 = __shfl(pk[lo][0], s1lane), b2 = __shfl(pk[hi][0], s1lane);
        const uint32_t a3 = __shfl(pk[lo][1], s1lane), b3 = __shfl(pk[hi][1], s1lane);
        uint4 uu;
        uu.x = ghi ? b0 : a0; uu.y = ghi ? b1 : a1;
        uu.z = ghi ? b2 : a2; uu.w = ghi ? b3 : a3;
        const bfrag pfrag = __builtin_bit_cast(bfrag, uu);
#pragma unroll
        for (int et = 0; et < 4; ++et)
          accT[qf][et] = __builtin_amdgcn_mfma_f32_16x16x32_bf16(vb[kc][et], pfrag, accT[qf][et], 0, 0, 0);
      }
      __builtin_amdgcn_s_setprio(0);
    }

    // rotate K double buffer
#pragma unroll
    for (int tt = 0; tt < 4; ++tt)
#pragma unroll
      for (int kh = 0; kh < 2; ++kh)
        kcur[kh][tt] = knxt[kh][tt];
  }

  // finalize: L reduce over the 4 g-lanes (same l15), normalize, store O^T rows
#pragma unroll
  for (int qf = 0; qf < 2; ++qf) {
    float Ls = Ll[qf];
    Ls += __shfl_xor(Ls, 16);
    Ls += __shfl_xor(Ls, 32);
    const float inv = 1.f / Ls;
    u16* orow = Og + (size_t)(q0 + qf * 16 + l15) * 1024 + g * 4;
#pragma unroll
    for (int et = 0; et < 4; ++et) {
      uint2 w;
      w.x = cvtpk(accT[qf][et][0] * inv, accT[qf][et][1] * inv);
      w.y = cvtpk(accT[qf][et][2] * inv, accT[qf][et][3] * inv);
      *(uint2*)(orow + et * 16) = w;
    }
  }
}

extern "C" void kernel_launch(void* const* d_in, const int* in_sizes, int n_in,
                              void* d_out, int out_size, void* d_ws, size_t ws_size,
                              hipStream_t stream) {
  const float* keys    = (const float*)d_in[0];
  const float* queries = (const float*)d_in[1];
  const float* values  = (const float*)d_in[2];
  const float* Wq = (const float*)d_in[3];
  const float* bq = (const float*)d_in[4];
  const float* Wk = (const float*)d_in[5];
  const float* bk = (const float*)d_in[6];
  const float* Wv = (const float*)d_in[7];
  const float* bv = (const float*)d_in[8];
  const float* Wo = (const float*)d_in[9];
  const float* bo = (const float*)d_in[10];
  float* out = (float*)d_out;

  char* ws = (char*)d_ws;
  const size_t MB = 1u << 20;
  u16* Wqkvt = (u16*)(ws);               // 6 MB
  u16* Wot   = (u16*)(ws + 6 * MB);      // 2 MB
  u16* Qb    = (u16*)(ws + 8 * MB);      // 16 MB
  u16* Kb    = (u16*)(ws + 24 * MB);
  u16* Vtg   = (u16*)(ws + 40 * MB);
  u16* Ob    = (u16*)(ws + 56 * MB);

  const dim3 pg(16, 16);
  pack_w_hde<<<pg, 256, 0, stream>>>(Wq, Wqkvt);
  pack_w_hde<<<pg, 256, 0, stream>>>(Wk, Wqkvt + (size_t)1024 * 1024);
  pack_w_hde<<<pg, 256, 0, stream>>>(Wv, Wqkvt + (size_t)2048 * 1024);
  transpose_w<<<pg, 256, 0, stream>>>(Wo, Wot);

  gemm_qkv<<<dim3(1536), 256, 0, stream>>>(queries, keys, values, Wqkvt,
                                           bq, bk, bv, Qb, Kb, Vtg);

  attn_fused<<<dim3(4096), 64, 0, stream>>>(Qb, Kb, Vtg, Ob);

  gemm_o<<<dim3(512), 256, 0, stream>>>(Ob, Wot, bo, out);
}

// Round 11
// 246.807 us; speedup vs baseline: 1.0005x; 1.0005x over previous
//
#include <hip/hip_runtime.h>
#include <stdint.h>

typedef unsigned short u16;
typedef __attribute__((ext_vector_type(4))) float f32x4;
typedef __attribute__((ext_vector_type(8))) short bfrag;

static __device__ __forceinline__ u16 f2bf(float f) {  // RNE
  union { float f; uint32_t u; } v; v.f = f;
  return (u16)((v.u + 0x7fffu + ((v.u >> 16) & 1u)) >> 16);
}
// pack two f32 -> packed bf16x2 (RNE) in one instruction
static __device__ __forceinline__ uint32_t cvtpk(float lo, float hi) {
  uint32_t r;
  asm("v_cvt_pk_bf16_f32 %0, %1, %2" : "=v"(r) : "v"(lo), "v"(hi));
  return r;
}
// pack two f32 -> packed bf16x2 (round-half-up) in one v_perm
static __device__ __forceinline__ uint32_t pk2bf(float lo, float hi) {
  union { float f; uint32_t u; } a, b; a.f = lo; b.f = hi;
  return __builtin_amdgcn_perm(b.u + 0x8000u, a.u + 0x8000u, 0x07060302u);
}

#define GLOAD16(gp, lp)                                              \
  __builtin_amdgcn_global_load_lds(                                  \
      (const __attribute__((address_space(1))) uint32_t*)(gp),       \
      (__attribute__((address_space(3))) uint32_t*)(lp), 16, 0, 0)

// ---------------- pack W: [1024][64] f32 slice -> Wt[h*64+e][k] bf16
__global__ __launch_bounds__(256) void pack_w_hde(const float* __restrict__ W,
                                                  u16* __restrict__ Wt) {
  __shared__ float tile[64][65];
  const int h = blockIdx.y, k0 = blockIdx.x * 64;
  const int tid = threadIdx.x;
#pragma unroll
  for (int j = 0; j < 4; ++j) {
    int idx = tid + j * 256;
    int rr = idx >> 4, c4 = (idx & 15) * 4;
    const float4 v = *(const float4*)(W + (size_t)h * 65536 + (size_t)(k0 + rr) * 64 + c4);
    tile[rr][c4 + 0] = v.x; tile[rr][c4 + 1] = v.y;
    tile[rr][c4 + 2] = v.z; tile[rr][c4 + 3] = v.w;
  }
  __syncthreads();
#pragma unroll
  for (int j = 0; j < 4; ++j) {
    int idx = tid + j * 256;
    int ee = idx >> 4, c4 = (idx & 15) * 4;
    uint2 u;
    u.x = f2bf(tile[c4 + 0][ee]) | ((uint32_t)f2bf(tile[c4 + 1][ee]) << 16);
    u.y = f2bf(tile[c4 + 2][ee]) | ((uint32_t)f2bf(tile[c4 + 3][ee]) << 16);
    *(uint2*)(Wt + (size_t)(h * 64 + ee) * 1024 + k0 + c4) = u;
  }
}

// ---------------- transpose Wo: [1024][1024] f32 -> bf16, out[n][k] = Wo[k][n]
__global__ __launch_bounds__(256) void transpose_w(const float* __restrict__ W,
                                                   u16* __restrict__ Wt) {
  __shared__ float tile[64][65];
  const int k0 = blockIdx.x * 64, n0 = blockIdx.y * 64;
  const int tid = threadIdx.x;
#pragma unroll
  for (int j = 0; j < 4; ++j) {
    int idx = tid + j * 256;
    int rr = idx >> 4, c4 = (idx & 15) * 4;
    const float4 v = *(const float4*)(W + (size_t)(k0 + rr) * 1024 + n0 + c4);
    tile[rr][c4 + 0] = v.x; tile[rr][c4 + 1] = v.y;
    tile[rr][c4 + 2] = v.z; tile[rr][c4 + 3] = v.w;
  }
  __syncthreads();
#pragma unroll
  for (int j = 0; j < 4; ++j) {
    int idx = tid + j * 256;
    int ee = idx >> 4, c4 = (idx & 15) * 4;
    uint2 u;
    u.x = f2bf(tile[c4 + 0][ee]) | ((uint32_t)f2bf(tile[c4 + 1][ee]) << 16);
    u.y = f2bf(tile[c4 + 2][ee]) | ((uint32_t)f2bf(tile[c4 + 3][ee]) << 16);
    *(uint2*)(Wt + (size_t)(n0 + ee) * 1024 + k0 + c4) = u;
  }
}

// ---------------- fused QKV GEMM: [8192,1024]f32 x Wqkv^T[3072][1024] + bias
// 2-phase pipelined, 1 barrier/K-step. Q chunk pre-scaled by 0.125.
__global__ __launch_bounds__(256) void gemm_qkv(
    const float* __restrict__ Aq, const float* __restrict__ Ak,
    const float* __restrict__ Avv, const u16* __restrict__ Bt,
    const float* __restrict__ bq, const float* __restrict__ bk,
    const float* __restrict__ bv,
    u16* __restrict__ Qb, u16* __restrict__ Kb, u16* __restrict__ Vt) {
  __shared__ u16 As[2][128 * 40];
  __shared__ u16 Bs[2][128 * 32];
  const int tid = threadIdx.x;
  const int n = blockIdx.x;
  const int xcd = n & 7, j = n >> 3;
  const int mb = xcd * 8 + (j & 7);   // 0..63
  const int nb = j >> 3;              // 0..23
  const int chunk = nb >> 3;          // 0:Q 1:K 2:V
  const float* Af = (chunk == 0) ? Aq : (chunk == 1) ? Ak : Avv;
  const int wid = tid >> 6, lane = tid & 63;
  const int wr = wid >> 1, wc = wid & 1;
  const int g = lane >> 4, l15 = lane & 15;
  f32x4 acc[4][4] = {};

  const u16* Bg = Bt + (size_t)(nb * 128 + 2 * wid * 16 + (lane >> 2)) * 1024 + (lane & 3) * 8;
  const float* Ap = Af + (size_t)(mb * 128 + (tid >> 2)) * 1024 + (tid & 3) * 8;
  const int arow = tid >> 2, ac8 = (tid & 3) * 8;

  float4 fa[2][2];
#pragma unroll
  for (int c = 0; c < 2; ++c) {
    fa[c][0] = *(const float4*)(Ap + (size_t)c * 64 * 1024);
    fa[c][1] = *(const float4*)(Ap + (size_t)c * 64 * 1024 + 4);
  }
#pragma unroll
  for (int c = 0; c < 2; ++c)
    GLOAD16(Bg + (size_t)c * 16 * 1024, &Bs[0][2 * wid * 512 + c * 512]);
#pragma unroll
  for (int c = 0; c < 2; ++c) {
    uint4 u;
    u.x = pk2bf(fa[c][0].x, fa[c][0].y); u.y = pk2bf(fa[c][0].z, fa[c][0].w);
    u.z = pk2bf(fa[c][1].x, fa[c][1].y); u.w = pk2bf(fa[c][1].z, fa[c][1].w);
    *(uint4*)&As[0][(arow + c * 64) * 40 + ac8] = u;
  }
  __syncthreads();
  int cur = 0;
  for (int kk = 0; kk < 32; ++kk) {
    if (kk < 31) {
      const int kn = (kk + 1) * 32;
#pragma unroll
      for (int c = 0; c < 2; ++c) {
        fa[c][0] = *(const float4*)(Ap + (size_t)c * 64 * 1024 + kn);
        fa[c][1] = *(const float4*)(Ap + (size_t)c * 64 * 1024 + kn + 4);
      }
#pragma unroll
      for (int c = 0; c < 2; ++c)
        GLOAD16(Bg + (size_t)c * 16 * 1024 + kn, &Bs[cur ^ 1][2 * wid * 512 + c * 512]);
    }
    bfrag a[4], b[4];
#pragma unroll
    for (int m = 0; m < 4; ++m)
      a[m] = __builtin_bit_cast(bfrag, *(const uint4*)&As[cur][(wr * 64 + m * 16 + l15) * 40 + g * 8]);
#pragma unroll
    for (int nn = 0; nn < 4; ++nn)
      b[nn] = __builtin_bit_cast(bfrag, *(const uint4*)&Bs[cur][(wc * 64 + nn * 16 + l15) * 32 + g * 8]);
    __builtin_amdgcn_s_setprio(1);
#pragma unroll
    for (int m = 0; m < 4; ++m)
#pragma unroll
      for (int nn = 0; nn < 4; ++nn)
        acc[m][nn] = __builtin_amdgcn_mfma_f32_16x16x32_bf16(a[m], b[nn], acc[m][nn], 0, 0, 0);
    __builtin_amdgcn_s_setprio(0);
    if (kk < 31) {
#pragma unroll
      for (int c = 0; c < 2; ++c) {
        uint4 u;
        u.x = pk2bf(fa[c][0].x, fa[c][0].y); u.y = pk2bf(fa[c][0].z, fa[c][0].w);
        u.z = pk2bf(fa[c][1].x, fa[c][1].y); u.w = pk2bf(fa[c][1].z, fa[c][1].w);
        *(uint4*)&As[cur ^ 1][(arow + c * 64) * 40 + ac8] = u;
      }
      __syncthreads();
      cur ^= 1;
    }
  }

  const int row0 = mb * 128 + wr * 64 + g * 4;
  const int cc0 = (nb & 7) * 128 + wc * 64 + l15;  // col within chunk, 0..1023
  const float* bias = (chunk == 0) ? bq : (chunk == 1) ? bk : bv;
  const float qs = (chunk == 0) ? 0.125f : 1.0f;
#pragma unroll
  for (int m = 0; m < 4; ++m) {
#pragma unroll
    for (int nn = 0; nn < 4; ++nn) {
      const int row = row0 + m * 16;
      const int cc = cc0 + nn * 16;
      const float bcv = bias[cc];
      if (chunk < 2) {
        u16* dst = (chunk == 0) ? Qb : Kb;
#pragma unroll
        for (int r = 0; r < 4; ++r)
          dst[(size_t)(row + r) * 1024 + cc] = f2bf((acc[m][nn][r] + bcv) * qs);
      } else {
        u16 w[4];
#pragma unroll
        for (int r = 0; r < 4; ++r) w[r] = f2bf(acc[m][nn][r] + bcv);
        const size_t dst =
            ((size_t)((row >> 11) * 16 + (cc >> 6)) * 64 + (cc & 63)) * 2048 + (row & 2047);
        *(uint2*)(Vt + dst) = *(const uint2*)w;
      }
    }
  }
}

// ---------------- O-projection GEMM: Ob bf16 [8192,1024] x Wot^T + bo -> f32
__global__ __launch_bounds__(256) void gemm_o(const u16* __restrict__ Abf,
                                              const u16* __restrict__ Bt,
                                              const float* __restrict__ bo,
                                              float* __restrict__ Of) {
  __shared__ u16 As[2][128 * 32];
  __shared__ u16 Bs[2][128 * 32];
  const int tid = threadIdx.x;
  const int n = blockIdx.x;
  const int xcd = n & 7, j = n >> 3;
  const int mb = xcd * 8 + (j & 7);   // 0..63
  const int nb = j >> 3;              // 0..7
  const int wid = tid >> 6, lane = tid & 63;
  const int wr = wid >> 1, wc = wid & 1;
  const int g = lane >> 4, l15 = lane & 15;
  f32x4 acc[4][4] = {};

  const u16* Bg = Bt + (size_t)(nb * 128 + 2 * wid * 16 + (lane >> 2)) * 1024 + (lane & 3) * 8;
  const u16* Ag = Abf + (size_t)(mb * 128 + 2 * wid * 16 + (lane >> 2)) * 1024 + (lane & 3) * 8;

#pragma unroll
  for (int c = 0; c < 2; ++c) {
    GLOAD16(Ag + (size_t)c * 16 * 1024, &As[0][2 * wid * 512 + c * 512]);
    GLOAD16(Bg + (size_t)c * 16 * 1024, &Bs[0][2 * wid * 512 + c * 512]);
  }
  __syncthreads();
  int cur = 0;
  for (int kk = 0; kk < 32; ++kk) {
    if (kk < 31) {
      const int kn = (kk + 1) * 32;
#pragma unroll
      for (int c = 0; c < 2; ++c) {
        GLOAD16(Ag + (size_t)c * 16 * 1024 + kn, &As[cur ^ 1][2 * wid * 512 + c * 512]);
        GLOAD16(Bg + (size_t)c * 16 * 1024 + kn, &Bs[cur ^ 1][2 * wid * 512 + c * 512]);
      }
    }
    bfrag a[4], b[4];
#pragma unroll
    for (int m = 0; m < 4; ++m)
      a[m] = __builtin_bit_cast(bfrag, *(const uint4*)&As[cur][(wr * 64 + m * 16 + l15) * 32 + g * 8]);
#pragma unroll
    for (int nn = 0; nn < 4; ++nn)
      b[nn] = __builtin_bit_cast(bfrag, *(const uint4*)&Bs[cur][(wc * 64 + nn * 16 + l15) * 32 + g * 8]);
    __builtin_amdgcn_s_setprio(1);
#pragma unroll
    for (int m = 0; m < 4; ++m)
#pragma unroll
      for (int nn = 0; nn < 4; ++nn)
        acc[m][nn] = __builtin_amdgcn_mfma_f32_16x16x32_bf16(a[m], b[nn], acc[m][nn], 0, 0, 0);
    __builtin_amdgcn_s_setprio(0);
    if (kk < 31) { __syncthreads(); cur ^= 1; }
  }

  const int row0 = mb * 128 + wr * 64 + g * 4;
  const int col0 = nb * 128 + wc * 64 + l15;
#pragma unroll
  for (int m = 0; m < 4; ++m)
#pragma unroll
    for (int nn = 0; nn < 4; ++nn) {
      const int row = row0 + m * 16, col = col0 + nn * 16;
      const float bcv = bo[col];
#pragma unroll
      for (int r = 0; r < 4; ++r)
        Of[(size_t)(row + r) * 1024 + col] = acc[m][nn][r] + bcv;
    }
}

// ---------------- fused causal flash attention — swapped operands, zero LDS,
// SCORE-PREFETCH software pipeline: sc(s+1) = QK(s+1) is issued in the middle
// of step s (right after softmax consumes sc(s), before shuffles+PV), so the
// QK MFMA latency hides under PV + the other qf pass + next-step load issue.
// Q (pre-scaled 1/8), K bf16 [B*S,1024]; Vtg bf16 [B*H][64e][2048s]; O bf16.
// 4096 blocks x 64 thr: ONE wave per block, one 32-row q-tile per wave.
__global__ __launch_bounds__(64) void attn_fused(const u16* __restrict__ Qb,
                                                 const u16* __restrict__ Kb,
                                                 const u16* __restrict__ Vtg,
                                                 u16* __restrict__ Ob) {
  const int lane = threadIdx.x & 63;
  const int g = lane >> 4, l15 = lane & 15;
  const int n = blockIdx.x;
  const int xcd = n & 7, j = n >> 3;     // j 0..511
  const int bh = xcd * 8 + (j & 7);
  const int t = 63 - (j >> 3);           // tile 0..63, longest first
  const int b = bh >> 4, h = bh & 15;
  const size_t baserow = (size_t)b * 2048;
  const u16* Qg = Qb + baserow * 1024 + h * 64;
  const u16* Kg = Kb + baserow * 1024 + h * 64;
  const u16* Vg = Vtg + (size_t)bh * 64 * 2048;
  u16* Og = Ob + baserow * 1024 + h * 64;

  const int q0 = t * 32;
  const int qrow = q0 + l15;             // this lane's q for qf=0 (+16 for qf=1)

  bfrag qa[2][2];
#pragma unroll
  for (int qf = 0; qf < 2; ++qf)
#pragma unroll
    for (int kh = 0; kh < 2; ++kh)
      qa[qf][kh] = __builtin_bit_cast(bfrag,
          *(const uint4*)(Qg + (size_t)(q0 + qf * 16 + l15) * 1024 + kh * 32 + g * 8));

  f32x4 accT[2][4] = {};      // [qf][et]: lane holds e=et*16+g*4+r, q=l15
  float M[2] = {-1e30f, -1e30f}, Ll[2] = {0.f, 0.f};

  const int s0lane = ((g & 1) << 5) | l15;   // source lane for frag u0/u1
  const int s1lane = s0lane + 16;            // source lane for frag u2/u3
  const bool ghi = (g >= 2);

  const int nsteps = (q0 >> 6) + 1;

  // K fragment row pointer for this lane (row = kv + tt*16 + l15)
  const u16* Krow = Kg + (size_t)l15 * 1024 + g * 8;

  // prologue: K(0) + sc = QK(0)
  bfrag kc[2][4];
#pragma unroll
  for (int tt = 0; tt < 4; ++tt)
#pragma unroll
    for (int kh = 0; kh < 2; ++kh)
      kc[kh][tt] = __builtin_bit_cast(bfrag,
          *(const uint4*)(Krow + (size_t)(tt * 16) * 1024 + kh * 32));
  f32x4 sc[2][4];
#pragma unroll
  for (int qf = 0; qf < 2; ++qf)
#pragma unroll
    for (int tt = 0; tt < 4; ++tt) {
      f32x4 z = {0.f, 0.f, 0.f, 0.f};
      z = __builtin_amdgcn_mfma_f32_16x16x32_bf16(kc[0][tt], qa[qf][0], z, 0, 0, 0);
      z = __builtin_amdgcn_mfma_f32_16x16x32_bf16(kc[1][tt], qa[qf][1], z, 0, 0, 0);
      sc[qf][tt] = z;
    }

  for (int s = 0; s < nsteps; ++s) {
    const int kv0 = s << 6;
    const bool diag = (s == nsteps - 1);
    const bool more = (s + 1 < nsteps);

    // V(s) loads (consumed at PV after softmax+QK-prefetch: ample slack)
    bfrag vb[2][4];
#pragma unroll
    for (int et = 0; et < 4; ++et)
#pragma unroll
      for (int kcb = 0; kcb < 2; ++kcb)
        vb[kcb][et] = __builtin_bit_cast(bfrag,
            *(const uint4*)(Vg + (size_t)(et * 16 + l15) * 2048 + kv0 + kcb * 32 + g * 8));

    // K(s+1) loads (consumed at the in-step QK prefetch; softmax covers them)
    if (more) {
      const int kn = (s + 1) << 6;
#pragma unroll
      for (int tt = 0; tt < 4; ++tt)
#pragma unroll
        for (int kh = 0; kh < 2; ++kh)
          kc[kh][tt] = __builtin_bit_cast(bfrag,
              *(const uint4*)(Krow + (size_t)(kn + tt * 16) * 1024 + kh * 32));
    }

#pragma unroll
    for (int qf = 0; qf < 2; ++qf) {
      if (diag) {
        const int qq = qrow + qf * 16;
#pragma unroll
        for (int tt = 0; tt < 4; ++tt) {
          const int kvb = kv0 + tt * 16 + g * 4;
#pragma unroll
          for (int r = 0; r < 4; ++r)
            sc[qf][tt][r] = (kvb + r <= qq) ? sc[qf][tt][r] : -1e30f;
        }
      }
      // lane-local max over 16 values
      float m01 = fmaxf(fmaxf(sc[qf][0][0], sc[qf][0][1]), fmaxf(sc[qf][0][2], sc[qf][0][3]));
      float m23 = fmaxf(fmaxf(sc[qf][1][0], sc[qf][1][1]), fmaxf(sc[qf][1][2], sc[qf][1][3]));
      float m45 = fmaxf(fmaxf(sc[qf][2][0], sc[qf][2][1]), fmaxf(sc[qf][2][2], sc[qf][2][3]));
      float m67 = fmaxf(fmaxf(sc[qf][3][0], sc[qf][3][1]), fmaxf(sc[qf][3][2], sc[qf][3][3]));
      const float mloc = fmaxf(fmaxf(m01, m23), fmaxf(m45, m67));
      if (!__all(mloc - M[qf] <= 6.0f)) {  // rare: true row max + rescale
        float mr = fmaxf(mloc, __shfl_xor(mloc, 16));
        mr = fmaxf(mr, __shfl_xor(mr, 32));
        const float Mn = fmaxf(M[qf], mr);
        const float cf = __expf(M[qf] - Mn);
        M[qf] = Mn;
        Ll[qf] *= cf;
#pragma unroll
        for (int et = 0; et < 4; ++et)
#pragma unroll
          for (int r = 0; r < 4; ++r) accT[qf][et][r] *= cf;
      }
      // exp + lane-local L accumulation + bf16 pair packing (consumes sc[qf])
      uint32_t pk[4][2];
      float ss = 0.f;
#pragma unroll
      for (int tt = 0; tt < 4; ++tt) {
        float p0 = __expf(sc[qf][tt][0] - M[qf]);
        float p1 = __expf(sc[qf][tt][1] - M[qf]);
        float p2 = __expf(sc[qf][tt][2] - M[qf]);
        float p3 = __expf(sc[qf][tt][3] - M[qf]);
        ss += (p0 + p1) + (p2 + p3);
        pk[tt][0] = cvtpk(p0, p1);
        pk[tt][1] = cvtpk(p2, p3);
      }
      Ll[qf] += ss;

      // SCORE PREFETCH: sc[qf] <- QK(s+1) issued NOW, consumed next iteration
      // (latency hidden under the shuffles+PV below + the other qf pass).
      if (more) {
        __builtin_amdgcn_s_setprio(1);
#pragma unroll
        for (int tt = 0; tt < 4; ++tt) {
          f32x4 z = {0.f, 0.f, 0.f, 0.f};
          z = __builtin_amdgcn_mfma_f32_16x16x32_bf16(kc[0][tt], qa[qf][0], z, 0, 0, 0);
          z = __builtin_amdgcn_mfma_f32_16x16x32_bf16(kc[1][tt], qa[qf][1], z, 0, 0, 0);
          sc[qf][tt] = z;
        }
        __builtin_amdgcn_s_setprio(0);
      }

      // build P^T B-operand fragments via lane shuffles (DS pipe, overlaps QK):
      // target lane (g,l15) kc-frag holds kv = kcb*32 + g*8 .. +7 for q=l15.
      __builtin_amdgcn_s_setprio(1);
#pragma unroll
      for (int kcb = 0; kcb < 2; ++kcb) {
        const int lo = kcb * 2, hi = kcb * 2 + 1;
        const uint32_t a0 = __shfl(pk[lo][0], s0lane), b0 = __shfl(pk[hi][0], s0lane);
        const uint32_t a1 = __shfl(pk[lo][1], s0lane), b1 = __shfl(pk[hi][1], s0lane);
        const uint32_t a2 = __shfl(pk[lo][0], s1lane), b2 = __shfl(pk[hi][0], s1lane);
        const uint32_t a3 = __shfl(pk[lo][1], s1lane), b3 = __shfl(pk[hi][1], s1lane);
        uint4 uu;
        uu.x = ghi ? b0 : a0; uu.y = ghi ? b1 : a1;
        uu.z = ghi ? b2 : a2; uu.w = ghi ? b3 : a3;
        const bfrag pfrag = __builtin_bit_cast(bfrag, uu);
#pragma unroll
        for (int et = 0; et < 4; ++et)
          accT[qf][et] = __builtin_amdgcn_mfma_f32_16x16x32_bf16(vb[kcb][et], pfrag, accT[qf][et], 0, 0, 0);
      }
      __builtin_amdgcn_s_setprio(0);
    }
  }

  // finalize: L reduce over the 4 g-lanes (same l15), normalize, store O^T rows
#pragma unroll
  for (int qf = 0; qf < 2; ++qf) {
    float Ls = Ll[qf];
    Ls += __shfl_xor(Ls, 16);
    Ls += __shfl_xor(Ls, 32);
    const float inv = 1.f / Ls;
    u16* orow = Og + (size_t)(q0 + qf * 16 + l15) * 1024 + g * 4;
#pragma unroll
    for (int et = 0; et < 4; ++et) {
      uint2 w;
      w.x = cvtpk(accT[qf][et][0] * inv, accT[qf][et][1] * inv);
      w.y = cvtpk(accT[qf][et][2] * inv, accT[qf][et][3] * inv);
      *(uint2*)(orow + et * 16) = w;
    }
  }
}

extern "C" void kernel_launch(void* const* d_in, const int* in_sizes, int n_in,
                              void* d_out, int out_size, void* d_ws, size_t ws_size,
                              hipStream_t stream) {
  const float* keys    = (const float*)d_in[0];
  const float* queries = (const float*)d_in[1];
  const float* values  = (const float*)d_in[2];
  const float* Wq = (const float*)d_in[3];
  const float* bq = (const float*)d_in[4];
  const float* Wk = (const float*)d_in[5];
  const float* bk = (const float*)d_in[6];
  const float* Wv = (const float*)d_in[7];
  const float* bv = (const float*)d_in[8];
  const float* Wo = (const float*)d_in[9];
  const float* bo = (const float*)d_in[10];
  float* out = (float*)d_out;

  char* ws = (char*)d_ws;
  const size_t MB = 1u << 20;
  u16* Wqkvt = (u16*)(ws);               // 6 MB
  u16* Wot   = (u16*)(ws + 6 * MB);      // 2 MB
  u16* Qb    = (u16*)(ws + 8 * MB);      // 16 MB
  u16* Kb    = (u16*)(ws + 24 * MB);
  u16* Vtg   = (u16*)(ws + 40 * MB);
  u16* Ob    = (u16*)(ws + 56 * MB);

  const dim3 pg(16, 16);
  pack_w_hde<<<pg, 256, 0, stream>>>(Wq, Wqkvt);
  pack_w_hde<<<pg, 256, 0, stream>>>(Wk, Wqkvt + (size_t)1024 * 1024);
  pack_w_hde<<<pg, 256, 0, stream>>>(Wv, Wqkvt + (size_t)2048 * 1024);
  transpose_w<<<pg, 256, 0, stream>>>(Wo, Wot);

  gemm_qkv<<<dim3(1536), 256, 0, stream>>>(queries, keys, values, Wqkvt,
                                           bq, bk, bv, Qb, Kb, Vtg);

  attn_fused<<<dim3(4096), 64, 0, stream>>>(Qb, Kb, Vtg, Ob);

  gemm_o<<<dim3(512), 256, 0, stream>>>(Ob, Wot, bo, out);
}

// Round 12
// 198.701 us; speedup vs baseline: 1.2427x; 1.2421x over previous
//
#include <hip/hip_runtime.h>
#include <stdint.h>

typedef unsigned short u16;
typedef __attribute__((ext_vector_type(4))) float f32x4;
typedef __attribute__((ext_vector_type(8))) short bfrag;

static __device__ __forceinline__ u16 f2bf(float f) {  // RNE
  union { float f; uint32_t u; } v; v.f = f;
  return (u16)((v.u + 0x7fffu + ((v.u >> 16) & 1u)) >> 16);
}
// pack two f32 -> packed bf16x2 (RNE) in one instruction
static __device__ __forceinline__ uint32_t cvtpk(float lo, float hi) {
  uint32_t r;
  asm("v_cvt_pk_bf16_f32 %0, %1, %2" : "=v"(r) : "v"(lo), "v"(hi));
  return r;
}
// pack two f32 -> packed bf16x2 (round-half-up) in one v_perm
static __device__ __forceinline__ uint32_t pk2bf(float lo, float hi) {
  union { float f; uint32_t u; } a, b; a.f = lo; b.f = hi;
  return __builtin_amdgcn_perm(b.u + 0x8000u, a.u + 0x8000u, 0x07060302u);
}

#define GLOAD16(gp, lp)                                              \
  __builtin_amdgcn_global_load_lds(                                  \
      (const __attribute__((address_space(1))) uint32_t*)(gp),       \
      (__attribute__((address_space(3))) uint32_t*)(lp), 16, 0, 0)

// ---------------- pack W: [1024][64] f32 slice -> Wt[h*64+e][k] bf16
__global__ __launch_bounds__(256) void pack_w_hde(const float* __restrict__ W,
                                                  u16* __restrict__ Wt) {
  __shared__ float tile[64][65];
  const int h = blockIdx.y, k0 = blockIdx.x * 64;
  const int tid = threadIdx.x;
#pragma unroll
  for (int j = 0; j < 4; ++j) {
    int idx = tid + j * 256;
    int rr = idx >> 4, c4 = (idx & 15) * 4;
    const float4 v = *(const float4*)(W + (size_t)h * 65536 + (size_t)(k0 + rr) * 64 + c4);
    tile[rr][c4 + 0] = v.x; tile[rr][c4 + 1] = v.y;
    tile[rr][c4 + 2] = v.z; tile[rr][c4 + 3] = v.w;
  }
  __syncthreads();
#pragma unroll
  for (int j = 0; j < 4; ++j) {
    int idx = tid + j * 256;
    int ee = idx >> 4, c4 = (idx & 15) * 4;
    uint2 u;
    u.x = f2bf(tile[c4 + 0][ee]) | ((uint32_t)f2bf(tile[c4 + 1][ee]) << 16);
    u.y = f2bf(tile[c4 + 2][ee]) | ((uint32_t)f2bf(tile[c4 + 3][ee]) << 16);
    *(uint2*)(Wt + (size_t)(h * 64 + ee) * 1024 + k0 + c4) = u;
  }
}

// ---------------- transpose Wo: [1024][1024] f32 -> bf16, out[n][k] = Wo[k][n]
__global__ __launch_bounds__(256) void transpose_w(const float* __restrict__ W,
                                                   u16* __restrict__ Wt) {
  __shared__ float tile[64][65];
  const int k0 = blockIdx.x * 64, n0 = blockIdx.y * 64;
  const int tid = threadIdx.x;
#pragma unroll
  for (int j = 0; j < 4; ++j) {
    int idx = tid + j * 256;
    int rr = idx >> 4, c4 = (idx & 15) * 4;
    const float4 v = *(const float4*)(W + (size_t)(k0 + rr) * 1024 + n0 + c4);
    tile[rr][c4 + 0] = v.x; tile[rr][c4 + 1] = v.y;
    tile[rr][c4 + 2] = v.z; tile[rr][c4 + 3] = v.w;
  }
  __syncthreads();
#pragma unroll
  for (int j = 0; j < 4; ++j) {
    int idx = tid + j * 256;
    int ee = idx >> 4, c4 = (idx & 15) * 4;
    uint2 u;
    u.x = f2bf(tile[c4 + 0][ee]) | ((uint32_t)f2bf(tile[c4 + 1][ee]) << 16);
    u.y = f2bf(tile[c4 + 2][ee]) | ((uint32_t)f2bf(tile[c4 + 3][ee]) << 16);
    *(uint2*)(Wt + (size_t)(n0 + ee) * 1024 + k0 + c4) = u;
  }
}

// ---------------- fused QKV GEMM: [8192,1024]f32 x Wqkv^T[3072][1024] + bias
// 2-phase pipelined, 1 barrier/K-step. Q chunk pre-scaled by 0.125.
__global__ __launch_bounds__(256) void gemm_qkv(
    const float* __restrict__ Aq, const float* __restrict__ Ak,
    const float* __restrict__ Avv, const u16* __restrict__ Bt,
    const float* __restrict__ bq, const float* __restrict__ bk,
    const float* __restrict__ bv,
    u16* __restrict__ Qb, u16* __restrict__ Kb, u16* __restrict__ Vt) {
  __shared__ u16 As[2][128 * 40];
  __shared__ u16 Bs[2][128 * 32];
  const int tid = threadIdx.x;
  const int n = blockIdx.x;
  const int xcd = n & 7, j = n >> 3;
  const int mb = xcd * 8 + (j & 7);   // 0..63
  const int nb = j >> 3;              // 0..23
  const int chunk = nb >> 3;          // 0:Q 1:K 2:V
  const float* Af = (chunk == 0) ? Aq : (chunk == 1) ? Ak : Avv;
  const int wid = tid >> 6, lane = tid & 63;
  const int wr = wid >> 1, wc = wid & 1;
  const int g = lane >> 4, l15 = lane & 15;
  f32x4 acc[4][4] = {};

  const u16* Bg = Bt + (size_t)(nb * 128 + 2 * wid * 16 + (lane >> 2)) * 1024 + (lane & 3) * 8;
  const float* Ap = Af + (size_t)(mb * 128 + (tid >> 2)) * 1024 + (tid & 3) * 8;
  const int arow = tid >> 2, ac8 = (tid & 3) * 8;

  float4 fa[2][2];
#pragma unroll
  for (int c = 0; c < 2; ++c) {
    fa[c][0] = *(const float4*)(Ap + (size_t)c * 64 * 1024);
    fa[c][1] = *(const float4*)(Ap + (size_t)c * 64 * 1024 + 4);
  }
#pragma unroll
  for (int c = 0; c < 2; ++c)
    GLOAD16(Bg + (size_t)c * 16 * 1024, &Bs[0][2 * wid * 512 + c * 512]);
#pragma unroll
  for (int c = 0; c < 2; ++c) {
    uint4 u;
    u.x = pk2bf(fa[c][0].x, fa[c][0].y); u.y = pk2bf(fa[c][0].z, fa[c][0].w);
    u.z = pk2bf(fa[c][1].x, fa[c][1].y); u.w = pk2bf(fa[c][1].z, fa[c][1].w);
    *(uint4*)&As[0][(arow + c * 64) * 40 + ac8] = u;
  }
  __syncthreads();
  int cur = 0;
  for (int kk = 0; kk < 32; ++kk) {
    if (kk < 31) {
      const int kn = (kk + 1) * 32;
#pragma unroll
      for (int c = 0; c < 2; ++c) {
        fa[c][0] = *(const float4*)(Ap + (size_t)c * 64 * 1024 + kn);
        fa[c][1] = *(const float4*)(Ap + (size_t)c * 64 * 1024 + kn + 4);
      }
#pragma unroll
      for (int c = 0; c < 2; ++c)
        GLOAD16(Bg + (size_t)c * 16 * 1024 + kn, &Bs[cur ^ 1][2 * wid * 512 + c * 512]);
    }
    bfrag a[4], b[4];
#pragma unroll
    for (int m = 0; m < 4; ++m)
      a[m] = __builtin_bit_cast(bfrag, *(const uint4*)&As[cur][(wr * 64 + m * 16 + l15) * 40 + g * 8]);
#pragma unroll
    for (int nn = 0; nn < 4; ++nn)
      b[nn] = __builtin_bit_cast(bfrag, *(const uint4*)&Bs[cur][(wc * 64 + nn * 16 + l15) * 32 + g * 8]);
    __builtin_amdgcn_s_setprio(1);
#pragma unroll
    for (int m = 0; m < 4; ++m)
#pragma unroll
      for (int nn = 0; nn < 4; ++nn)
        acc[m][nn] = __builtin_amdgcn_mfma_f32_16x16x32_bf16(a[m], b[nn], acc[m][nn], 0, 0, 0);
    __builtin_amdgcn_s_setprio(0);
    if (kk < 31) {
#pragma unroll
      for (int c = 0; c < 2; ++c) {
        uint4 u;
        u.x = pk2bf(fa[c][0].x, fa[c][0].y); u.y = pk2bf(fa[c][0].z, fa[c][0].w);
        u.z = pk2bf(fa[c][1].x, fa[c][1].y); u.w = pk2bf(fa[c][1].z, fa[c][1].w);
        *(uint4*)&As[cur ^ 1][(arow + c * 64) * 40 + ac8] = u;
      }
      __syncthreads();
      cur ^= 1;
    }
  }

  const int row0 = mb * 128 + wr * 64 + g * 4;
  const int cc0 = (nb & 7) * 128 + wc * 64 + l15;  // col within chunk, 0..1023
  const float* bias = (chunk == 0) ? bq : (chunk == 1) ? bk : bv;
  const float qs = (chunk == 0) ? 0.125f : 1.0f;
#pragma unroll
  for (int m = 0; m < 4; ++m) {
#pragma unroll
    for (int nn = 0; nn < 4; ++nn) {
      const int row = row0 + m * 16;
      const int cc = cc0 + nn * 16;
      const float bcv = bias[cc];
      if (chunk < 2) {
        u16* dst = (chunk == 0) ? Qb : Kb;
#pragma unroll
        for (int r = 0; r < 4; ++r)
          dst[(size_t)(row + r) * 1024 + cc] = f2bf((acc[m][nn][r] + bcv) * qs);
      } else {
        u16 w[4];
#pragma unroll
        for (int r = 0; r < 4; ++r) w[r] = f2bf(acc[m][nn][r] + bcv);
        const size_t dst =
            ((size_t)((row >> 11) * 16 + (cc >> 6)) * 64 + (cc & 63)) * 2048 + (row & 2047);
        *(uint2*)(Vt + dst) = *(const uint2*)w;
      }
    }
  }
}

// ---------------- O-projection GEMM: Ob bf16 [8192,1024] x Wot^T + bo -> f32
__global__ __launch_bounds__(256) void gemm_o(const u16* __restrict__ Abf,
                                              const u16* __restrict__ Bt,
                                              const float* __restrict__ bo,
                                              float* __restrict__ Of) {
  __shared__ u16 As[2][128 * 32];
  __shared__ u16 Bs[2][128 * 32];
  const int tid = threadIdx.x;
  const int n = blockIdx.x;
  const int xcd = n & 7, j = n >> 3;
  const int mb = xcd * 8 + (j & 7);   // 0..63
  const int nb = j >> 3;              // 0..7
  const int wid = tid >> 6, lane = tid & 63;
  const int wr = wid >> 1, wc = wid & 1;
  const int g = lane >> 4, l15 = lane & 15;
  f32x4 acc[4][4] = {};

  const u16* Bg = Bt + (size_t)(nb * 128 + 2 * wid * 16 + (lane >> 2)) * 1024 + (lane & 3) * 8;
  const u16* Ag = Abf + (size_t)(mb * 128 + 2 * wid * 16 + (lane >> 2)) * 1024 + (lane & 3) * 8;

#pragma unroll
  for (int c = 0; c < 2; ++c) {
    GLOAD16(Ag + (size_t)c * 16 * 1024, &As[0][2 * wid * 512 + c * 512]);
    GLOAD16(Bg + (size_t)c * 16 * 1024, &Bs[0][2 * wid * 512 + c * 512]);
  }
  __syncthreads();
  int cur = 0;
  for (int kk = 0; kk < 32; ++kk) {
    if (kk < 31) {
      const int kn = (kk + 1) * 32;
#pragma unroll
      for (int c = 0; c < 2; ++c) {
        GLOAD16(Ag + (size_t)c * 16 * 1024 + kn, &As[cur ^ 1][2 * wid * 512 + c * 512]);
        GLOAD16(Bg + (size_t)c * 16 * 1024 + kn, &Bs[cur ^ 1][2 * wid * 512 + c * 512]);
      }
    }
    bfrag a[4], b[4];
#pragma unroll
    for (int m = 0; m < 4; ++m)
      a[m] = __builtin_bit_cast(bfrag, *(const uint4*)&As[cur][(wr * 64 + m * 16 + l15) * 32 + g * 8]);
#pragma unroll
    for (int nn = 0; nn < 4; ++nn)
      b[nn] = __builtin_bit_cast(bfrag, *(const uint4*)&Bs[cur][(wc * 64 + nn * 16 + l15) * 32 + g * 8]);
    __builtin_amdgcn_s_setprio(1);
#pragma unroll
    for (int m = 0; m < 4; ++m)
#pragma unroll
      for (int nn = 0; nn < 4; ++nn)
        acc[m][nn] = __builtin_amdgcn_mfma_f32_16x16x32_bf16(a[m], b[nn], acc[m][nn], 0, 0, 0);
    __builtin_amdgcn_s_setprio(0);
    if (kk < 31) { __syncthreads(); cur ^= 1; }
  }

  const int row0 = mb * 128 + wr * 64 + g * 4;
  const int col0 = nb * 128 + wc * 64 + l15;
#pragma unroll
  for (int m = 0; m < 4; ++m)
#pragma unroll
    for (int nn = 0; nn < 4; ++nn) {
      const int row = row0 + m * 16, col = col0 + nn * 16;
      const float bcv = bo[col];
#pragma unroll
      for (int r = 0; r < 4; ++r)
        Of[(size_t)(row + r) * 1024 + col] = acc[m][nn][r] + bcv;
    }
}

// ---------------- fused causal flash attention — swapped operands, LDS-staged
// K/V with XOR swizzle, double-buffered cooperative staging.
// Q (pre-scaled 1/8), K bf16 [B*S,1024]; Vtg bf16 [B*H][64e][2048s]; O bf16.
// 512 blocks x 512 thr (8 waves). Block = one (b,h) x 8 consecutive q-tiles
// (wave w -> tile u*8+w). Per step the block cooperatively stages the 64x64
// K and V tiles into LDS (global_load_lds, 16B/thread each) with the source
// address pre-swizzled so LDS chunk c of row r holds global chunk c^(r&7)
// (m173 pattern); fragment ds_reads apply the same XOR -> 2-way banks (free).
// Double-buffered: stage(s+1) issued before compute(s); 1 barrier/step.
// u-groups {7..4} dispatched first, {0..3} second -> CU block-pairs sum to
// uniform work. Per-wave compute is R9's proven register-only path.
__global__ __launch_bounds__(512) void attn_fused(const u16* __restrict__ Qb,
                                                  const u16* __restrict__ Kb,
                                                  const u16* __restrict__ Vtg,
                                                  u16* __restrict__ Ob) {
  __shared__ u16 KV[2][2][4096];   // [dbuf][K,V][64 rows x 64 cols], swizzled
  const int tid = threadIdx.x;
  const int wid = tid >> 6, lane = tid & 63;
  const int g = lane >> 4, l15 = lane & 15;
  const int n = blockIdx.x;
  const int half = n >> 8, idx = n & 255;
  const int xcd = idx & 7;
  const int bh = xcd * 8 + ((idx >> 3) & 7);
  const int grp = idx >> 6;                 // 0..3
  const int u = half ? grp : (7 - grp);     // tile-group 0..7, longest first
  const int t = u * 8 + wid;                // this wave's 32-row q-tile
  const int b = bh >> 4, h = bh & 15;
  const size_t baserow = (size_t)b * 2048;
  const u16* Qg = Qb + baserow * 1024 + h * 64;
  const u16* Kg = Kb + baserow * 1024 + h * 64;
  const u16* Vg = Vtg + (size_t)bh * 64 * 2048;
  u16* Og = Ob + baserow * 1024 + h * 64;

  const int q0 = t * 32;
  const int qrow = q0 + l15;
  const int mysteps = (q0 >> 6) + 1;
  const int smax = 4 * u + 4;               // steps of the block's longest tile

  // staging coords: thread stages 16B of K and 16B of V per buffer.
  // LDS linear slot = tid*16B -> row sr = tid>>3, chunk c = tid&7; the global
  // chunk fetched is c ^ (sr&7) (inverse swizzle on the SOURCE).
  const int sr = tid >> 3;
  const int scc = (tid & 7) ^ (sr & 7);
  const u16* Kst = Kg + (size_t)sr * 1024 + scc * 8;
  const u16* Vst = Vg + (size_t)sr * 2048 + scc * 8;

  bfrag qa[2][2];
#pragma unroll
  for (int qf = 0; qf < 2; ++qf)
#pragma unroll
    for (int kh = 0; kh < 2; ++kh)
      qa[qf][kh] = __builtin_bit_cast(bfrag,
          *(const uint4*)(Qg + (size_t)(q0 + qf * 16 + l15) * 1024 + kh * 32 + g * 8));

  f32x4 accT[2][4] = {};      // [qf][et]: lane holds e=et*16+g*4+r, q=l15
  float M[2] = {-1e30f, -1e30f}, Ll[2] = {0.f, 0.f};

  const int s0lane = ((g & 1) << 5) | l15;   // source lane for P frag u0/u1
  const int s1lane = s0lane + 16;            // source lane for P frag u2/u3
  const bool ghi = (g >= 2);
  const int swz = l15 & 7;                   // read-side XOR (row&7)

  // prologue: stage KV(0) into buf 0
  GLOAD16(Kst, &KV[0][0][wid * 512]);
  GLOAD16(Vst, &KV[0][1][wid * 512]);
  __syncthreads();

  for (int s = 0; s < smax; ++s) {
    const int cb = s & 1;
    if (s + 1 < smax) {  // issue next-tile staging (lands by next barrier)
      const size_t kn = (size_t)(s + 1) << 6;
      GLOAD16(Kst + kn * 1024, &KV[cb ^ 1][0][wid * 512]);
      GLOAD16(Vst + kn, &KV[cb ^ 1][1][wid * 512]);
    }
    if (s < mysteps) {
      const int kv0 = s << 6;
      const bool diag = (s == mysteps - 1);
      const u16* KB = &KV[cb][0][0];
      const u16* VB = &KV[cb][1][0];

      bfrag kb[2][4];
#pragma unroll
      for (int tt = 0; tt < 4; ++tt)
#pragma unroll
        for (int kh = 0; kh < 2; ++kh)
          kb[kh][tt] = __builtin_bit_cast(bfrag,
              *(const uint4*)&KB[(tt * 16 + l15) * 64 + (((kh << 2) | g) ^ swz) * 8]);

      // S^T = K * Q^T : lane (g,l15) holds S[q=q0+qf*16+l15][kv0+tt*16+g*4+r]
      f32x4 sc[2][4];
      __builtin_amdgcn_s_setprio(1);
#pragma unroll
      for (int qf = 0; qf < 2; ++qf)
#pragma unroll
        for (int tt = 0; tt < 4; ++tt) {
          f32x4 z = {0.f, 0.f, 0.f, 0.f};
          z = __builtin_amdgcn_mfma_f32_16x16x32_bf16(kb[0][tt], qa[qf][0], z, 0, 0, 0);
          z = __builtin_amdgcn_mfma_f32_16x16x32_bf16(kb[1][tt], qa[qf][1], z, 0, 0, 0);
          sc[qf][tt] = z;
        }
      __builtin_amdgcn_s_setprio(0);

      bfrag vb[2][4];
#pragma unroll
      for (int et = 0; et < 4; ++et)
#pragma unroll
        for (int kcb = 0; kcb < 2; ++kcb)
          vb[kcb][et] = __builtin_bit_cast(bfrag,
              *(const uint4*)&VB[(et * 16 + l15) * 64 + (((kcb << 2) | g) ^ swz) * 8]);

#pragma unroll
      for (int qf = 0; qf < 2; ++qf) {
        if (diag) {
          const int qq = qrow + qf * 16;
#pragma unroll
          for (int tt = 0; tt < 4; ++tt) {
            const int kvb = kv0 + tt * 16 + g * 4;
#pragma unroll
            for (int r = 0; r < 4; ++r)
              sc[qf][tt][r] = (kvb + r <= qq) ? sc[qf][tt][r] : -1e30f;
          }
        }
        // lane-local max over 16 values
        float m01 = fmaxf(fmaxf(sc[qf][0][0], sc[qf][0][1]), fmaxf(sc[qf][0][2], sc[qf][0][3]));
        float m23 = fmaxf(fmaxf(sc[qf][1][0], sc[qf][1][1]), fmaxf(sc[qf][1][2], sc[qf][1][3]));
        float m45 = fmaxf(fmaxf(sc[qf][2][0], sc[qf][2][1]), fmaxf(sc[qf][2][2], sc[qf][2][3]));
        float m67 = fmaxf(fmaxf(sc[qf][3][0], sc[qf][3][1]), fmaxf(sc[qf][3][2], sc[qf][3][3]));
        const float mloc = fmaxf(fmaxf(m01, m23), fmaxf(m45, m67));
        if (!__all(mloc - M[qf] <= 6.0f)) {  // rare: true row max + rescale
          float mr = fmaxf(mloc, __shfl_xor(mloc, 16));
          mr = fmaxf(mr, __shfl_xor(mr, 32));
          const float Mn = fmaxf(M[qf], mr);
          const float cf = __expf(M[qf] - Mn);
          M[qf] = Mn;
          Ll[qf] *= cf;
#pragma unroll
          for (int et = 0; et < 4; ++et)
#pragma unroll
            for (int r = 0; r < 4; ++r) accT[qf][et][r] *= cf;
        }
        // exp + lane-local L accumulation + bf16 pair packing
        uint32_t pk[4][2];
        float ss = 0.f;
#pragma unroll
        for (int tt = 0; tt < 4; ++tt) {
          float p0 = __expf(sc[qf][tt][0] - M[qf]);
          float p1 = __expf(sc[qf][tt][1] - M[qf]);
          float p2 = __expf(sc[qf][tt][2] - M[qf]);
          float p3 = __expf(sc[qf][tt][3] - M[qf]);
          ss += (p0 + p1) + (p2 + p3);
          pk[tt][0] = cvtpk(p0, p1);
          pk[tt][1] = cvtpk(p2, p3);
        }
        Ll[qf] += ss;
        // build P^T B-operand fragments via lane shuffles:
        // target lane (g,l15) kcb-frag holds kv = kcb*32 + g*8 .. +7 for q=l15.
        __builtin_amdgcn_s_setprio(1);
#pragma unroll
        for (int kcb = 0; kcb < 2; ++kcb) {
          const int lo = kcb * 2, hi = kcb * 2 + 1;
          const uint32_t a0 = __shfl(pk[lo][0], s0lane), b0 = __shfl(pk[hi][0], s0lane);
          const uint32_t a1 = __shfl(pk[lo][1], s0lane), b1 = __shfl(pk[hi][1], s0lane);
          const uint32_t a2 = __shfl(pk[lo][0], s1lane), b2 = __shfl(pk[hi][0], s1lane);
          const uint32_t a3 = __shfl(pk[lo][1], s1lane), b3 = __shfl(pk[hi][1], s1lane);
          uint4 uu;
          uu.x = ghi ? b0 : a0; uu.y = ghi ? b1 : a1;
          uu.z = ghi ? b2 : a2; uu.w = ghi ? b3 : a3;
          const bfrag pfrag = __builtin_bit_cast(bfrag, uu);
#pragma unroll
          for (int et = 0; et < 4; ++et)
            accT[qf][et] = __builtin_amdgcn_mfma_f32_16x16x32_bf16(vb[kcb][et], pfrag, accT[qf][et], 0, 0, 0);
        }
        __builtin_amdgcn_s_setprio(0);
      }
    }
    __syncthreads();  // staging complete + buffer reads retired
  }

  // finalize: L reduce over the 4 g-lanes (same l15), normalize, store O^T rows
#pragma unroll
  for (int qf = 0; qf < 2; ++qf) {
    float Ls = Ll[qf];
    Ls += __shfl_xor(Ls, 16);
    Ls += __shfl_xor(Ls, 32);
    const float inv = 1.f / Ls;
    u16* orow = Og + (size_t)(q0 + qf * 16 + l15) * 1024 + g * 4;
#pragma unroll
    for (int et = 0; et < 4; ++et) {
      uint2 w;
      w.x = cvtpk(accT[qf][et][0] * inv, accT[qf][et][1] * inv);
      w.y = cvtpk(accT[qf][et][2] * inv, accT[qf][et][3] * inv);
      *(uint2*)(orow + et * 16) = w;
    }
  }
}

extern "C" void kernel_launch(void* const* d_in, const int* in_sizes, int n_in,
                              void* d_out, int out_size, void* d_ws, size_t ws_size,
                              hipStream_t stream) {
  const float* keys    = (const float*)d_in[0];
  const float* queries = (const float*)d_in[1];
  const float* values  = (const float*)d_in[2];
  const float* Wq = (const float*)d_in[3];
  const float* bq = (const float*)d_in[4];
  const float* Wk = (const float*)d_in[5];
  const float* bk = (const float*)d_in[6];
  const float* Wv = (const float*)d_in[7];
  const float* bv = (const float*)d_in[8];
  const float* Wo = (const float*)d_in[9];
  const float* bo = (const float*)d_in[10];
  float* out = (float*)d_out;

  char* ws = (char*)d_ws;
  const size_t MB = 1u << 20;
  u16* Wqkvt = (u16*)(ws);               // 6 MB
  u16* Wot   = (u16*)(ws + 6 * MB);      // 2 MB
  u16* Qb    = (u16*)(ws + 8 * MB);      // 16 MB
  u16* Kb    = (u16*)(ws + 24 * MB);
  u16* Vtg   = (u16*)(ws + 40 * MB);
  u16* Ob    = (u16*)(ws + 56 * MB);

  const dim3 pg(16, 16);
  pack_w_hde<<<pg, 256, 0, stream>>>(Wq, Wqkvt);
  pack_w_hde<<<pg, 256, 0, stream>>>(Wk, Wqkvt + (size_t)1024 * 1024);
  pack_w_hde<<<pg, 256, 0, stream>>>(Wv, Wqkvt + (size_t)2048 * 1024);
  transpose_w<<<pg, 256, 0, stream>>>(Wo, Wot);

  gemm_qkv<<<dim3(1536), 256, 0, stream>>>(queries, keys, values, Wqkvt,
                                           bq, bk, bv, Qb, Kb, Vtg);

  attn_fused<<<dim3(512), 512, 0, stream>>>(Qb, Kb, Vtg, Ob);

  gemm_o<<<dim3(512), 256, 0, stream>>>(Ob, Wot, bo, out);
}

// Round 13
// 197.537 us; speedup vs baseline: 1.2500x; 1.0059x over previous
//
#include <hip/hip_runtime.h>
#include <stdint.h>

typedef unsigned short u16;
typedef __attribute__((ext_vector_type(4))) float f32x4;
typedef __attribute__((ext_vector_type(8))) short bfrag;

static __device__ __forceinline__ u16 f2bf(float f) {  // RNE
  union { float f; uint32_t u; } v; v.f = f;
  return (u16)((v.u + 0x7fffu + ((v.u >> 16) & 1u)) >> 16);
}
// pack two f32 -> packed bf16x2 (RNE) in one instruction
static __device__ __forceinline__ uint32_t cvtpk(float lo, float hi) {
  uint32_t r;
  asm("v_cvt_pk_bf16_f32 %0, %1, %2" : "=v"(r) : "v"(lo), "v"(hi));
  return r;
}
// pack two f32 -> packed bf16x2 (round-half-up) in one v_perm
static __device__ __forceinline__ uint32_t pk2bf(float lo, float hi) {
  union { float f; uint32_t u; } a, b; a.f = lo; b.f = hi;
  return __builtin_amdgcn_perm(b.u + 0x8000u, a.u + 0x8000u, 0x07060302u);
}

#define GLOAD16(gp, lp)                                              \
  __builtin_amdgcn_global_load_lds(                                  \
      (const __attribute__((address_space(1))) uint32_t*)(gp),       \
      (__attribute__((address_space(3))) uint32_t*)(lp), 16, 0, 0)

// ---------------- pack W: [1024][64] f32 slice -> Wt[h*64+e][k] bf16
__global__ __launch_bounds__(256) void pack_w_hde(const float* __restrict__ W,
                                                  u16* __restrict__ Wt) {
  __shared__ float tile[64][65];
  const int h = blockIdx.y, k0 = blockIdx.x * 64;
  const int tid = threadIdx.x;
#pragma unroll
  for (int j = 0; j < 4; ++j) {
    int idx = tid + j * 256;
    int rr = idx >> 4, c4 = (idx & 15) * 4;
    const float4 v = *(const float4*)(W + (size_t)h * 65536 + (size_t)(k0 + rr) * 64 + c4);
    tile[rr][c4 + 0] = v.x; tile[rr][c4 + 1] = v.y;
    tile[rr][c4 + 2] = v.z; tile[rr][c4 + 3] = v.w;
  }
  __syncthreads();
#pragma unroll
  for (int j = 0; j < 4; ++j) {
    int idx = tid + j * 256;
    int ee = idx >> 4, c4 = (idx & 15) * 4;
    uint2 u;
    u.x = f2bf(tile[c4 + 0][ee]) | ((uint32_t)f2bf(tile[c4 + 1][ee]) << 16);
    u.y = f2bf(tile[c4 + 2][ee]) | ((uint32_t)f2bf(tile[c4 + 3][ee]) << 16);
    *(uint2*)(Wt + (size_t)(h * 64 + ee) * 1024 + k0 + c4) = u;
  }
}

// ---------------- transpose Wo: [1024][1024] f32 -> bf16, out[n][k] = Wo[k][n]
__global__ __launch_bounds__(256) void transpose_w(const float* __restrict__ W,
                                                   u16* __restrict__ Wt) {
  __shared__ float tile[64][65];
  const int k0 = blockIdx.x * 64, n0 = blockIdx.y * 64;
  const int tid = threadIdx.x;
#pragma unroll
  for (int j = 0; j < 4; ++j) {
    int idx = tid + j * 256;
    int rr = idx >> 4, c4 = (idx & 15) * 4;
    const float4 v = *(const float4*)(W + (size_t)(k0 + rr) * 1024 + n0 + c4);
    tile[rr][c4 + 0] = v.x; tile[rr][c4 + 1] = v.y;
    tile[rr][c4 + 2] = v.z; tile[rr][c4 + 3] = v.w;
  }
  __syncthreads();
#pragma unroll
  for (int j = 0; j < 4; ++j) {
    int idx = tid + j * 256;
    int ee = idx >> 4, c4 = (idx & 15) * 4;
    uint2 u;
    u.x = f2bf(tile[c4 + 0][ee]) | ((uint32_t)f2bf(tile[c4 + 1][ee]) << 16);
    u.y = f2bf(tile[c4 + 2][ee]) | ((uint32_t)f2bf(tile[c4 + 3][ee]) << 16);
    *(uint2*)(Wt + (size_t)(n0 + ee) * 1024 + k0 + c4) = u;
  }
}

// ---------------- fused QKV GEMM: [8192,1024]f32 x Wqkv^T[3072][1024] + bias
// 2-phase pipelined, 1 barrier/K-step. Q chunk pre-scaled by 0.125.
// LDS tiles [128][32] u16 with XOR chunk swizzle chunk^=(row>>1)&3:
//  - B staged via global_load_lds (linear dest) with pre-swizzled SOURCE col
//  - A (f32->bf16 reg path) swizzles the ds_write col directly
//  - fragment reads use chunk = g ^ ((l15>>1)&3)  -> 2-way banks (free)
__global__ __launch_bounds__(256) void gemm_qkv(
    const float* __restrict__ Aq, const float* __restrict__ Ak,
    const float* __restrict__ Avv, const u16* __restrict__ Bt,
    const float* __restrict__ bq, const float* __restrict__ bk,
    const float* __restrict__ bv,
    u16* __restrict__ Qb, u16* __restrict__ Kb, u16* __restrict__ Vt) {
  __shared__ u16 As[2][128 * 32];
  __shared__ u16 Bs[2][128 * 32];
  const int tid = threadIdx.x;
  const int n = blockIdx.x;
  const int xcd = n & 7, j = n >> 3;
  const int mb = xcd * 8 + (j & 7);   // 0..63
  const int nb = j >> 3;              // 0..23
  const int chunk = nb >> 3;          // 0:Q 1:K 2:V
  const float* Af = (chunk == 0) ? Aq : (chunk == 1) ? Ak : Avv;
  const int wid = tid >> 6, lane = tid & 63;
  const int wr = wid >> 1, wc = wid & 1;
  const int g = lane >> 4, l15 = lane & 15;
  f32x4 acc[4][4] = {};

  // B staging: linear LDS dest; source col chunk pre-swizzled
  const int bsrc = ((lane & 3) ^ ((lane >> 3) & 3)) * 8;
  const u16* Bg = Bt + (size_t)(nb * 128 + 2 * wid * 16 + (lane >> 2)) * 1024 + bsrc;
  const float* Ap = Af + (size_t)(mb * 128 + (tid >> 2)) * 1024 + (tid & 3) * 8;
  const int arow = tid >> 2;
  const int acs = (((tid & 3) ^ ((tid >> 3) & 3))) * 8;  // swizzled LDS col
  const int swzr = (l15 >> 1) & 3;                       // read-side XOR

  float4 fa[2][2];
#pragma unroll
  for (int c = 0; c < 2; ++c) {
    fa[c][0] = *(const float4*)(Ap + (size_t)c * 64 * 1024);
    fa[c][1] = *(const float4*)(Ap + (size_t)c * 64 * 1024 + 4);
  }
#pragma unroll
  for (int c = 0; c < 2; ++c)
    GLOAD16(Bg + (size_t)c * 16 * 1024, &Bs[0][2 * wid * 512 + c * 512]);
#pragma unroll
  for (int c = 0; c < 2; ++c) {
    uint4 u;
    u.x = pk2bf(fa[c][0].x, fa[c][0].y); u.y = pk2bf(fa[c][0].z, fa[c][0].w);
    u.z = pk2bf(fa[c][1].x, fa[c][1].y); u.w = pk2bf(fa[c][1].z, fa[c][1].w);
    *(uint4*)&As[0][(arow + c * 64) * 32 + acs] = u;
  }
  __syncthreads();
  int cur = 0;
  for (int kk = 0; kk < 32; ++kk) {
    if (kk < 31) {
      const int kn = (kk + 1) * 32;
#pragma unroll
      for (int c = 0; c < 2; ++c) {
        fa[c][0] = *(const float4*)(Ap + (size_t)c * 64 * 1024 + kn);
        fa[c][1] = *(const float4*)(Ap + (size_t)c * 64 * 1024 + kn + 4);
      }
#pragma unroll
      for (int c = 0; c < 2; ++c)
        GLOAD16(Bg + (size_t)c * 16 * 1024 + kn, &Bs[cur ^ 1][2 * wid * 512 + c * 512]);
    }
    bfrag a[4], b[4];
#pragma unroll
    for (int m = 0; m < 4; ++m)
      a[m] = __builtin_bit_cast(bfrag,
          *(const uint4*)&As[cur][(wr * 64 + m * 16 + l15) * 32 + ((g ^ swzr)) * 8]);
#pragma unroll
    for (int nn = 0; nn < 4; ++nn)
      b[nn] = __builtin_bit_cast(bfrag,
          *(const uint4*)&Bs[cur][(wc * 64 + nn * 16 + l15) * 32 + ((g ^ swzr)) * 8]);
    __builtin_amdgcn_s_setprio(1);
#pragma unroll
    for (int m = 0; m < 4; ++m)
#pragma unroll
      for (int nn = 0; nn < 4; ++nn)
        acc[m][nn] = __builtin_amdgcn_mfma_f32_16x16x32_bf16(a[m], b[nn], acc[m][nn], 0, 0, 0);
    __builtin_amdgcn_s_setprio(0);
    if (kk < 31) {
#pragma unroll
      for (int c = 0; c < 2; ++c) {
        uint4 u;
        u.x = pk2bf(fa[c][0].x, fa[c][0].y); u.y = pk2bf(fa[c][0].z, fa[c][0].w);
        u.z = pk2bf(fa[c][1].x, fa[c][1].y); u.w = pk2bf(fa[c][1].z, fa[c][1].w);
        *(uint4*)&As[cur ^ 1][(arow + c * 64) * 32 + acs] = u;
      }
      __syncthreads();
      cur ^= 1;
    }
  }

  const int row0 = mb * 128 + wr * 64 + g * 4;
  const int cc0 = (nb & 7) * 128 + wc * 64 + l15;  // col within chunk, 0..1023
  const float* bias = (chunk == 0) ? bq : (chunk == 1) ? bk : bv;
  const float qs = (chunk == 0) ? 0.125f : 1.0f;
#pragma unroll
  for (int m = 0; m < 4; ++m) {
#pragma unroll
    for (int nn = 0; nn < 4; ++nn) {
      const int row = row0 + m * 16;
      const int cc = cc0 + nn * 16;
      const float bcv = bias[cc];
      if (chunk < 2) {
        u16* dst = (chunk == 0) ? Qb : Kb;
#pragma unroll
        for (int r = 0; r < 4; ++r)
          dst[(size_t)(row + r) * 1024 + cc] = f2bf((acc[m][nn][r] + bcv) * qs);
      } else {
        u16 w[4];
#pragma unroll
        for (int r = 0; r < 4; ++r) w[r] = f2bf(acc[m][nn][r] + bcv);
        const size_t dst =
            ((size_t)((row >> 11) * 16 + (cc >> 6)) * 64 + (cc & 63)) * 2048 + (row & 2047);
        *(uint2*)(Vt + dst) = *(const uint2*)w;
      }
    }
  }
}

// ---------------- O-projection GEMM: Ob bf16 [8192,1024] x Wot^T + bo -> f32
// Same XOR chunk swizzle on both A and B (source-swizzled global_load_lds).
__global__ __launch_bounds__(256) void gemm_o(const u16* __restrict__ Abf,
                                              const u16* __restrict__ Bt,
                                              const float* __restrict__ bo,
                                              float* __restrict__ Of) {
  __shared__ u16 As[2][128 * 32];
  __shared__ u16 Bs[2][128 * 32];
  const int tid = threadIdx.x;
  const int n = blockIdx.x;
  const int xcd = n & 7, j = n >> 3;
  const int mb = xcd * 8 + (j & 7);   // 0..63
  const int nb = j >> 3;              // 0..7
  const int wid = tid >> 6, lane = tid & 63;
  const int wr = wid >> 1, wc = wid & 1;
  const int g = lane >> 4, l15 = lane & 15;
  f32x4 acc[4][4] = {};

  const int bsrc = ((lane & 3) ^ ((lane >> 3) & 3)) * 8;
  const int swzr = (l15 >> 1) & 3;
  const u16* Bg = Bt + (size_t)(nb * 128 + 2 * wid * 16 + (lane >> 2)) * 1024 + bsrc;
  const u16* Ag = Abf + (size_t)(mb * 128 + 2 * wid * 16 + (lane >> 2)) * 1024 + bsrc;

#pragma unroll
  for (int c = 0; c < 2; ++c) {
    GLOAD16(Ag + (size_t)c * 16 * 1024, &As[0][2 * wid * 512 + c * 512]);
    GLOAD16(Bg + (size_t)c * 16 * 1024, &Bs[0][2 * wid * 512 + c * 512]);
  }
  __syncthreads();
  int cur = 0;
  for (int kk = 0; kk < 32; ++kk) {
    if (kk < 31) {
      const int kn = (kk + 1) * 32;
#pragma unroll
      for (int c = 0; c < 2; ++c) {
        GLOAD16(Ag + (size_t)c * 16 * 1024 + kn, &As[cur ^ 1][2 * wid * 512 + c * 512]);
        GLOAD16(Bg + (size_t)c * 16 * 1024 + kn, &Bs[cur ^ 1][2 * wid * 512 + c * 512]);
      }
    }
    bfrag a[4], b[4];
#pragma unroll
    for (int m = 0; m < 4; ++m)
      a[m] = __builtin_bit_cast(bfrag,
          *(const uint4*)&As[cur][(wr * 64 + m * 16 + l15) * 32 + ((g ^ swzr)) * 8]);
#pragma unroll
    for (int nn = 0; nn < 4; ++nn)
      b[nn] = __builtin_bit_cast(bfrag,
          *(const uint4*)&Bs[cur][(wc * 64 + nn * 16 + l15) * 32 + ((g ^ swzr)) * 8]);
    __builtin_amdgcn_s_setprio(1);
#pragma unroll
    for (int m = 0; m < 4; ++m)
#pragma unroll
      for (int nn = 0; nn < 4; ++nn)
        acc[m][nn] = __builtin_amdgcn_mfma_f32_16x16x32_bf16(a[m], b[nn], acc[m][nn], 0, 0, 0);
    __builtin_amdgcn_s_setprio(0);
    if (kk < 31) { __syncthreads(); cur ^= 1; }
  }

  const int row0 = mb * 128 + wr * 64 + g * 4;
  const int col0 = nb * 128 + wc * 64 + l15;
#pragma unroll
  for (int m = 0; m < 4; ++m)
#pragma unroll
    for (int nn = 0; nn < 4; ++nn) {
      const int row = row0 + m * 16, col = col0 + nn * 16;
      const float bcv = bo[col];
#pragma unroll
      for (int r = 0; r < 4; ++r)
        Of[(size_t)(row + r) * 1024 + col] = acc[m][nn][r] + bcv;
    }
}

// ---------------- fused causal flash attention — swapped operands, LDS-staged
// K/V with XOR swizzle, double-buffered cooperative staging. (R12, unchanged)
__global__ __launch_bounds__(512) void attn_fused(const u16* __restrict__ Qb,
                                                  const u16* __restrict__ Kb,
                                                  const u16* __restrict__ Vtg,
                                                  u16* __restrict__ Ob) {
  __shared__ u16 KV[2][2][4096];   // [dbuf][K,V][64 rows x 64 cols], swizzled
  const int tid = threadIdx.x;
  const int wid = tid >> 6, lane = tid & 63;
  const int g = lane >> 4, l15 = lane & 15;
  const int n = blockIdx.x;
  const int half = n >> 8, idx = n & 255;
  const int xcd = idx & 7;
  const int bh = xcd * 8 + ((idx >> 3) & 7);
  const int grp = idx >> 6;                 // 0..3
  const int u = half ? grp : (7 - grp);     // tile-group 0..7, longest first
  const int t = u * 8 + wid;                // this wave's 32-row q-tile
  const int b = bh >> 4, h = bh & 15;
  const size_t baserow = (size_t)b * 2048;
  const u16* Qg = Qb + baserow * 1024 + h * 64;
  const u16* Kg = Kb + baserow * 1024 + h * 64;
  const u16* Vg = Vtg + (size_t)bh * 64 * 2048;
  u16* Og = Ob + baserow * 1024 + h * 64;

  const int q0 = t * 32;
  const int qrow = q0 + l15;
  const int mysteps = (q0 >> 6) + 1;
  const int smax = 4 * u + 4;               // steps of the block's longest tile

  const int sr = tid >> 3;
  const int scc = (tid & 7) ^ (sr & 7);
  const u16* Kst = Kg + (size_t)sr * 1024 + scc * 8;
  const u16* Vst = Vg + (size_t)sr * 2048 + scc * 8;

  bfrag qa[2][2];
#pragma unroll
  for (int qf = 0; qf < 2; ++qf)
#pragma unroll
    for (int kh = 0; kh < 2; ++kh)
      qa[qf][kh] = __builtin_bit_cast(bfrag,
          *(const uint4*)(Qg + (size_t)(q0 + qf * 16 + l15) * 1024 + kh * 32 + g * 8));

  f32x4 accT[2][4] = {};      // [qf][et]: lane holds e=et*16+g*4+r, q=l15
  float M[2] = {-1e30f, -1e30f}, Ll[2] = {0.f, 0.f};

  const int s0lane = ((g & 1) << 5) | l15;   // source lane for P frag u0/u1
  const int s1lane = s0lane + 16;            // source lane for P frag u2/u3
  const bool ghi = (g >= 2);
  const int swz = l15 & 7;                   // read-side XOR (row&7)

  GLOAD16(Kst, &KV[0][0][wid * 512]);
  GLOAD16(Vst, &KV[0][1][wid * 512]);
  __syncthreads();

  for (int s = 0; s < smax; ++s) {
    const int cb = s & 1;
    if (s + 1 < smax) {
      const size_t kn = (size_t)(s + 1) << 6;
      GLOAD16(Kst + kn * 1024, &KV[cb ^ 1][0][wid * 512]);
      GLOAD16(Vst + kn, &KV[cb ^ 1][1][wid * 512]);
    }
    if (s < mysteps) {
      const int kv0 = s << 6;
      const bool diag = (s == mysteps - 1);
      const u16* KB = &KV[cb][0][0];
      const u16* VB = &KV[cb][1][0];

      bfrag kb[2][4];
#pragma unroll
      for (int tt = 0; tt < 4; ++tt)
#pragma unroll
        for (int kh = 0; kh < 2; ++kh)
          kb[kh][tt] = __builtin_bit_cast(bfrag,
              *(const uint4*)&KB[(tt * 16 + l15) * 64 + (((kh << 2) | g) ^ swz) * 8]);

      f32x4 sc[2][4];
      __builtin_amdgcn_s_setprio(1);
#pragma unroll
      for (int qf = 0; qf < 2; ++qf)
#pragma unroll
        for (int tt = 0; tt < 4; ++tt) {
          f32x4 z = {0.f, 0.f, 0.f, 0.f};
          z = __builtin_amdgcn_mfma_f32_16x16x32_bf16(kb[0][tt], qa[qf][0], z, 0, 0, 0);
          z = __builtin_amdgcn_mfma_f32_16x16x32_bf16(kb[1][tt], qa[qf][1], z, 0, 0, 0);
          sc[qf][tt] = z;
        }
      __builtin_amdgcn_s_setprio(0);

      bfrag vb[2][4];
#pragma unroll
      for (int et = 0; et < 4; ++et)
#pragma unroll
        for (int kcb = 0; kcb < 2; ++kcb)
          vb[kcb][et] = __builtin_bit_cast(bfrag,
              *(const uint4*)&VB[(et * 16 + l15) * 64 + (((kcb << 2) | g) ^ swz) * 8]);

#pragma unroll
      for (int qf = 0; qf < 2; ++qf) {
        if (diag) {
          const int qq = qrow + qf * 16;
#pragma unroll
          for (int tt = 0; tt < 4; ++tt) {
            const int kvb = kv0 + tt * 16 + g * 4;
#pragma unroll
            for (int r = 0; r < 4; ++r)
              sc[qf][tt][r] = (kvb + r <= qq) ? sc[qf][tt][r] : -1e30f;
          }
        }
        float m01 = fmaxf(fmaxf(sc[qf][0][0], sc[qf][0][1]), fmaxf(sc[qf][0][2], sc[qf][0][3]));
        float m23 = fmaxf(fmaxf(sc[qf][1][0], sc[qf][1][1]), fmaxf(sc[qf][1][2], sc[qf][1][3]));
        float m45 = fmaxf(fmaxf(sc[qf][2][0], sc[qf][2][1]), fmaxf(sc[qf][2][2], sc[qf][2][3]));
        float m67 = fmaxf(fmaxf(sc[qf][3][0], sc[qf][3][1]), fmaxf(sc[qf][3][2], sc[qf][3][3]));
        const float mloc = fmaxf(fmaxf(m01, m23), fmaxf(m45, m67));
        if (!__all(mloc - M[qf] <= 6.0f)) {
          float mr = fmaxf(mloc, __shfl_xor(mloc, 16));
          mr = fmaxf(mr, __shfl_xor(mr, 32));
          const float Mn = fmaxf(M[qf], mr);
          const float cf = __expf(M[qf] - Mn);
          M[qf] = Mn;
          Ll[qf] *= cf;
#pragma unroll
          for (int et = 0; et < 4; ++et)
#pragma unroll
            for (int r = 0; r < 4; ++r) accT[qf][et][r] *= cf;
        }
        uint32_t pk[4][2];
        float ss = 0.f;
#pragma unroll
        for (int tt = 0; tt < 4; ++tt) {
          float p0 = __expf(sc[qf][tt][0] - M[qf]);
          float p1 = __expf(sc[qf][tt][1] - M[qf]);
          float p2 = __expf(sc[qf][tt][2] - M[qf]);
          float p3 = __expf(sc[qf][tt][3] - M[qf]);
          ss += (p0 + p1) + (p2 + p3);
          pk[tt][0] = cvtpk(p0, p1);
          pk[tt][1] = cvtpk(p2, p3);
        }
        Ll[qf] += ss;
        __builtin_amdgcn_s_setprio(1);
#pragma unroll
        for (int kcb = 0; kcb < 2; ++kcb) {
          const int lo = kcb * 2, hi = kcb * 2 + 1;
          const uint32_t a0 = __shfl(pk[lo][0], s0lane), b0 = __shfl(pk[hi][0], s0lane);
          const uint32_t a1 = __shfl(pk[lo][1], s0lane), b1 = __shfl(pk[hi][1], s0lane);
          const uint32_t a2 = __shfl(pk[lo][0], s1lane), b2 = __shfl(pk[hi][0], s1lane);
          const uint32_t a3 = __shfl(pk[lo][1], s1lane), b3 = __shfl(pk[hi][1], s1lane);
          uint4 uu;
          uu.x = ghi ? b0 : a0; uu.y = ghi ? b1 : a1;
          uu.z = ghi ? b2 : a2; uu.w = ghi ? b3 : a3;
          const bfrag pfrag = __builtin_bit_cast(bfrag, uu);
#pragma unroll
          for (int et = 0; et < 4; ++et)
            accT[qf][et] = __builtin_amdgcn_mfma_f32_16x16x32_bf16(vb[kcb][et], pfrag, accT[qf][et], 0, 0, 0);
        }
        __builtin_amdgcn_s_setprio(0);
      }
    }
    __syncthreads();
  }

#pragma unroll
  for (int qf = 0; qf < 2; ++qf) {
    float Ls = Ll[qf];
    Ls += __shfl_xor(Ls, 16);
    Ls += __shfl_xor(Ls, 32);
    const float inv = 1.f / Ls;
    u16* orow = Og + (size_t)(q0 + qf * 16 + l15) * 1024 + g * 4;
#pragma unroll
    for (int et = 0; et < 4; ++et) {
      uint2 w;
      w.x = cvtpk(accT[qf][et][0] * inv, accT[qf][et][1] * inv);
      w.y = cvtpk(accT[qf][et][2] * inv, accT[qf][et][3] * inv);
      *(uint2*)(orow + et * 16) = w;
    }
  }
}

extern "C" void kernel_launch(void* const* d_in, const int* in_sizes, int n_in,
                              void* d_out, int out_size, void* d_ws, size_t ws_size,
                              hipStream_t stream) {
  const float* keys    = (const float*)d_in[0];
  const float* queries = (const float*)d_in[1];
  const float* values  = (const float*)d_in[2];
  const float* Wq = (const float*)d_in[3];
  const float* bq = (const float*)d_in[4];
  const float* Wk = (const float*)d_in[5];
  const float* bk = (const float*)d_in[6];
  const float* Wv = (const float*)d_in[7];
  const float* bv = (const float*)d_in[8];
  const float* Wo = (const float*)d_in[9];
  const float* bo = (const float*)d_in[10];
  float* out = (float*)d_out;

  char* ws = (char*)d_ws;
  const size_t MB = 1u << 20;
  u16* Wqkvt = (u16*)(ws);               // 6 MB
  u16* Wot   = (u16*)(ws + 6 * MB);      // 2 MB
  u16* Qb    = (u16*)(ws + 8 * MB);      // 16 MB
  u16* Kb    = (u16*)(ws + 24 * MB);
  u16* Vtg   = (u16*)(ws + 40 * MB);
  u16* Ob    = (u16*)(ws + 56 * MB);

  const dim3 pg(16, 16);
  pack_w_hde<<<pg, 256, 0, stream>>>(Wq, Wqkvt);
  pack_w_hde<<<pg, 256, 0, stream>>>(Wk, Wqkvt + (size_t)1024 * 1024);
  pack_w_hde<<<pg, 256, 0, stream>>>(Wv, Wqkvt + (size_t)2048 * 1024);
  transpose_w<<<pg, 256, 0, stream>>>(Wo, Wot);

  gemm_qkv<<<dim3(1536), 256, 0, stream>>>(queries, keys, values, Wqkvt,
                                           bq, bk, bv, Qb, Kb, Vtg);

  attn_fused<<<dim3(512), 512, 0, stream>>>(Qb, Kb, Vtg, Ob);

  gemm_o<<<dim3(512), 256, 0, stream>>>(Ob, Wot, bo, out);
}